// Round 6
// baseline (1306.774 us; speedup 1.0000x reference)
//
#include <hip/hip_runtime.h>

#define TT 512
#define BB 32
#define DD 64
#define HH 128
#define EE 256
#define NR 16384   // T*B rows

typedef _Float16 h2v __attribute__((ext_vector_type(2)));

// ---------- helpers ----------
static __device__ __forceinline__ float bflo(unsigned u){ return __uint_as_float(u << 16); }
static __device__ __forceinline__ float bfhi(unsigned u){ return __uint_as_float(u & 0xFFFF0000u); }
static __device__ __forceinline__ unsigned short f2bf(float x){
  unsigned u = __float_as_uint(x);
  return (unsigned short)((u + 0x7FFFu + ((u >> 16) & 1u)) >> 16);  // RNE
}
static __device__ __forceinline__ unsigned packbf(float a, float b){
  return (unsigned)f2bf(a) | ((unsigned)f2bf(b) << 16);
}
static __device__ __forceinline__ float sigmoidf_(float x){
  return 1.0f / (1.0f + __expf(-x));
}
static __device__ __forceinline__ float tanhf_(float x){
  float e = __expf(2.0f * x);
  return 1.0f - 2.0f / (e + 1.0f);
}
static __device__ __forceinline__ unsigned packh2(float a, float b){
  h2v v; v.x = (_Float16)a; v.y = (_Float16)b;
  return __builtin_bit_cast(unsigned, v);
}
#define BCH(u) __builtin_bit_cast(h2v, (u))
#define DOT2(a, b, c) __builtin_amdgcn_fdot2((a), (b), (c), false)

// ---------- K1: gi[r][dir*384+j] = bi[j] + sum_d (x*mask)[r][d] * Wi[j][d] ----------
__global__ __launch_bounds__(256, 2) void gi_kernel(
    const float* __restrict__ x, const float* __restrict__ mask,
    const float* __restrict__ WiF, const float* __restrict__ biF,
    const float* __restrict__ WiB, const float* __restrict__ biB,
    float* __restrict__ gi)
{
  int r = blockIdx.x * 256 + threadIdx.x;
  int dir = blockIdx.y;
  const float* Wi = dir ? WiB : WiF;
  const float* bi = dir ? biB : biF;
  int t = r >> 5, b = r & 31;
  const float* xr = x + ((size_t)b * TT + t) * DD;
  const float* mr = mask + ((size_t)b * TT + t) * DD;
  float a[64];
#pragma unroll
  for (int i = 0; i < 16; i++) {
    float4 xv = *(const float4*)(xr + i*4);
    float4 mv = *(const float4*)(mr + i*4);
    a[i*4+0] = xv.x*mv.x; a[i*4+1] = xv.y*mv.y; a[i*4+2] = xv.z*mv.z; a[i*4+3] = xv.w*mv.w;
  }
  float* g = gi + (size_t)r * 768 + dir * 384;
  for (int j = 0; j < 384; j += 4) {
    float acc0 = bi[j+0], acc1 = bi[j+1], acc2 = bi[j+2], acc3 = bi[j+3];
    const float* w = Wi + (size_t)j * 64;
#pragma unroll
    for (int k = 0; k < 64; k++) {
      float av = a[k];
      acc0 += av * w[k];
      acc1 += av * w[64 + k];
      acc2 += av * w[128 + k];
      acc3 += av * w[192 + k];
    }
    *(float4*)(g + j) = make_float4(acc0, acc1, acc2, acc3);
  }
}

// ---------- K2: GRU scan. One WG per (dir, b). 256 threads, 4 waves (1/SIMD). ----------
// h is SPREAD across a wave's lanes (1 u32 f16-pair per lane, one ds_read_b32),
// then broadcast via v_readlane -> SGPR operand of v_dot2_f32_f16. This keeps
// the per-step LDS return-bus traffic ~2KB (R5's per-lane b128 broadcast reads
// moved ~128KB/step through the 128B/cyc LDS pipe = the 2100cyc/step wall).
// stage1: thread tid owns rz output tid (full 128-dot, 64 readlane+dot2, no shfl).
// stage2: thread pair both compute n output tid>>1 (full 128-dot, redundant, no shfl).
__global__ __launch_bounds__(256)
__attribute__((amdgpu_waves_per_eu(1, 1)))
void scan_kernel(
    const float* __restrict__ gi,      // [16384][768]
    const float* __restrict__ WhF, const float* __restrict__ bhF,
    const float* __restrict__ WhB, const float* __restrict__ bhB,
    float* __restrict__ hc)
{
  int dir = blockIdx.x >> 5;
  int b = blockIdx.x & 31;
  const float* Wh = dir ? WhB : WhF;
  const float* bh = dir ? bhB : bhF;
  int tid = threadIdx.x;
  int j2 = tid >> 1;
  int lane = tid & 63;

  __shared__ float h_s[128];        // f32 state (for blend and r*h)
  __shared__ unsigned hs16[64];     // f16-packed h, wave-spread layout
  __shared__ unsigned rh16[64];     // f16-packed r*h
  __shared__ float z_s[128];

  // stage-1 weights: full row tid of Wh_rz (128 f32 -> 64 packed-f16 u32)
  const float* wp1 = Wh + (size_t)tid * 128;
#define LDA(n) unsigned A##n = packh2(wp1[2*(n)], wp1[2*(n)+1]);
  LDA(0) LDA(1) LDA(2) LDA(3) LDA(4) LDA(5) LDA(6) LDA(7)
  LDA(8) LDA(9) LDA(10) LDA(11) LDA(12) LDA(13) LDA(14) LDA(15)
  LDA(16) LDA(17) LDA(18) LDA(19) LDA(20) LDA(21) LDA(22) LDA(23)
  LDA(24) LDA(25) LDA(26) LDA(27) LDA(28) LDA(29) LDA(30) LDA(31)
  LDA(32) LDA(33) LDA(34) LDA(35) LDA(36) LDA(37) LDA(38) LDA(39)
  LDA(40) LDA(41) LDA(42) LDA(43) LDA(44) LDA(45) LDA(46) LDA(47)
  LDA(48) LDA(49) LDA(50) LDA(51) LDA(52) LDA(53) LDA(54) LDA(55)
  LDA(56) LDA(57) LDA(58) LDA(59) LDA(60) LDA(61) LDA(62) LDA(63)
#undef LDA
  // stage-2 weights: full row (256+j2) of Wh_n (pair-redundant)
  const float* wp2 = Wh + (size_t)(256 + j2) * 128;
#define LDB(n) unsigned B##n = packh2(wp2[2*(n)], wp2[2*(n)+1]);
  LDB(0) LDB(1) LDB(2) LDB(3) LDB(4) LDB(5) LDB(6) LDB(7)
  LDB(8) LDB(9) LDB(10) LDB(11) LDB(12) LDB(13) LDB(14) LDB(15)
  LDB(16) LDB(17) LDB(18) LDB(19) LDB(20) LDB(21) LDB(22) LDB(23)
  LDB(24) LDB(25) LDB(26) LDB(27) LDB(28) LDB(29) LDB(30) LDB(31)
  LDB(32) LDB(33) LDB(34) LDB(35) LDB(36) LDB(37) LDB(38) LDB(39)
  LDB(40) LDB(41) LDB(42) LDB(43) LDB(44) LDB(45) LDB(46) LDB(47)
  LDB(48) LDB(49) LDB(50) LDB(51) LDB(52) LDB(53) LDB(54) LDB(55)
  LDB(56) LDB(57) LDB(58) LDB(59) LDB(60) LDB(61) LDB(62) LDB(63)
#undef LDB

  float bh1 = bh[tid];
  float bh2 = bh[256 + j2];

  if (tid < 128) h_s[tid] = 0.0f;
  if (tid < 64)  hs16[tid] = 0u;
  __syncthreads();

  size_t row0 = dir ? ((size_t)(TT-1)*BB + b) : (size_t)b;
  const float* grow = gi + row0 * 768 + dir * 384;
  long dstep = (dir ? -(long)BB : (long)BB) * 768;
  float gi1v = grow[tid];
  float gi2v = grow[256 + j2];

  for (int s = 0; s < TT; s++) {
    // pin all 128 packed-weight u32s (proven scalar "+v" pattern)
#define PIN8(a,b_,c,d,e,f,g,hh) asm volatile("" : "+v"(a), "+v"(b_), "+v"(c), "+v"(d), "+v"(e), "+v"(f), "+v"(g), "+v"(hh));
    PIN8(A0,A1,A2,A3,A4,A5,A6,A7)
    PIN8(A8,A9,A10,A11,A12,A13,A14,A15)
    PIN8(A16,A17,A18,A19,A20,A21,A22,A23)
    PIN8(A24,A25,A26,A27,A28,A29,A30,A31)
    PIN8(A32,A33,A34,A35,A36,A37,A38,A39)
    PIN8(A40,A41,A42,A43,A44,A45,A46,A47)
    PIN8(A48,A49,A50,A51,A52,A53,A54,A55)
    PIN8(A56,A57,A58,A59,A60,A61,A62,A63)
    PIN8(B0,B1,B2,B3,B4,B5,B6,B7)
    PIN8(B8,B9,B10,B11,B12,B13,B14,B15)
    PIN8(B16,B17,B18,B19,B20,B21,B22,B23)
    PIN8(B24,B25,B26,B27,B28,B29,B30,B31)
    PIN8(B32,B33,B34,B35,B36,B37,B38,B39)
    PIN8(B40,B41,B42,B43,B44,B45,B46,B47)
    PIN8(B48,B49,B50,B51,B52,B53,B54,B55)
    PIN8(B56,B57,B58,B59,B60,B61,B62,B63)
#undef PIN8

    // prefetch next step's gi (coalesced; hidden under compute)
    const float* gnext = grow + dstep;
    float gi1n = 0.f, gi2n = 0.f;
    if (s + 1 < TT) { gi1n = gnext[tid]; gi2n = gnext[256 + j2]; }

    // spread h across lanes: ONE ds_read_b32 per thread
    unsigned hvec = hs16[lane];
    float hold = h_s[tid & 127];     // old h (2-way broadcast, free)

    // stage 1: full 128-dot via readlane(SGPR)-broadcast dot2
    float ya = 0.f, yb = 0.f, yc = 0.f, yd = 0.f;
#define S1(k, acc) { unsigned hu_ = (unsigned)__builtin_amdgcn_readlane((int)hvec, (k)); \
    acc = DOT2(BCH(A##k), BCH(hu_), acc); }
    S1(0,ya)  S1(1,yb)  S1(2,yc)  S1(3,yd)  S1(4,ya)  S1(5,yb)  S1(6,yc)  S1(7,yd)
    S1(8,ya)  S1(9,yb)  S1(10,yc) S1(11,yd) S1(12,ya) S1(13,yb) S1(14,yc) S1(15,yd)
    S1(16,ya) S1(17,yb) S1(18,yc) S1(19,yd) S1(20,ya) S1(21,yb) S1(22,yc) S1(23,yd)
    S1(24,ya) S1(25,yb) S1(26,yc) S1(27,yd) S1(28,ya) S1(29,yb) S1(30,yc) S1(31,yd)
    S1(32,ya) S1(33,yb) S1(34,yc) S1(35,yd) S1(36,ya) S1(37,yb) S1(38,yc) S1(39,yd)
    S1(40,ya) S1(41,yb) S1(42,yc) S1(43,yd) S1(44,ya) S1(45,yb) S1(46,yc) S1(47,yd)
    S1(48,ya) S1(49,yb) S1(50,yc) S1(51,yd) S1(52,ya) S1(53,yb) S1(54,yc) S1(55,yd)
    S1(56,ya) S1(57,yb) S1(58,yc) S1(59,yd) S1(60,ya) S1(61,yb) S1(62,yc) S1(63,yd)
#undef S1
    float y = (ya + yb) + (yc + yd);
    float sg = sigmoidf_(gi1v + y + bh1);
    if (tid < 128) {
      // r*h as f16, one b16 write per thread (2 lanes/dword = free)
      ((unsigned short*)rh16)[tid] = __builtin_bit_cast(unsigned short, (_Float16)(sg * hold));
    } else {
      z_s[tid - 128] = sg;
    }
    __syncthreads();   // barrier A: rh/z ready

    // spread rh, then stage 2: full 128-dot (pair-redundant)
    unsigned rvec = rh16[lane];
    float ca = 0.f, cb = 0.f, cc = 0.f, cd = 0.f;
#define S2(k, acc) { unsigned ru_ = (unsigned)__builtin_amdgcn_readlane((int)rvec, (k)); \
    acc = DOT2(BCH(B##k), BCH(ru_), acc); }
    S2(0,ca)  S2(1,cb)  S2(2,cc)  S2(3,cd)  S2(4,ca)  S2(5,cb)  S2(6,cc)  S2(7,cd)
    S2(8,ca)  S2(9,cb)  S2(10,cc) S2(11,cd) S2(12,ca) S2(13,cb) S2(14,cc) S2(15,cd)
    S2(16,ca) S2(17,cb) S2(18,cc) S2(19,cd) S2(20,ca) S2(21,cb) S2(22,cc) S2(23,cd)
    S2(24,ca) S2(25,cb) S2(26,cc) S2(27,cd) S2(28,ca) S2(29,cb) S2(30,cc) S2(31,cd)
    S2(32,ca) S2(33,cb) S2(34,cc) S2(35,cd) S2(36,ca) S2(37,cb) S2(38,cc) S2(39,cd)
    S2(40,ca) S2(41,cb) S2(42,cc) S2(43,cd) S2(44,ca) S2(45,cb) S2(46,cc) S2(47,cd)
    S2(48,ca) S2(49,cb) S2(50,cc) S2(51,cd) S2(52,ca) S2(53,cb) S2(54,cc) S2(55,cd)
    S2(56,ca) S2(57,cb) S2(58,cc) S2(59,cd) S2(60,ca) S2(61,cb) S2(62,cc) S2(63,cd)
#undef S2
    float y2 = (ca + cb) + (cc + cd);
    float nn = tanhf_(gi2v + y2 + bh2);
    float zv = z_s[j2];
    float hv_ = h_s[j2];                // old h (same-wave read precedes pair write)
    float hn = nn + zv * (hv_ - nn);    // (1-z)*n + z*h
    if ((tid & 1) == 0) {
      h_s[j2] = hn;
      ((unsigned short*)hs16)[j2] = __builtin_bit_cast(unsigned short, (_Float16)hn);
      int t = dir ? (TT - 1 - s) : s;
      hc[((size_t)t * BB + b) * EE + dir * HH + j2] = hn;
    }
    __syncthreads();   // barrier B: h updated for next step
    gi1v = gi1n; gi2v = gi2n;
    grow = gnext;
  }
}

// ---------- K3/K5: C[r][c] = bias[c] + sum_k A[r][k]*W[c][k]  (K=256) ----------
__global__ __launch_bounds__(256) void gemm_kernel(
    const float* __restrict__ A, const float* __restrict__ W,
    const float* __restrict__ bias, float* __restrict__ C,
    int N, int nChunks)
{
  __shared__ float As[64*260];       // padded stride 260
  __shared__ unsigned Ws[128*130];   // bf16 pairs, padded stride 130 u32
  int tid = threadIdx.x;
  int ty = tid >> 4, tx = tid & 15;
  int r0 = blockIdx.x * 64;

  for (int l = tid; l < 4096; l += 256) {        // 64 rows x 64 float4
    int row = l >> 6, kq = l & 63;
    float4 v = *(const float4*)(A + (size_t)(r0 + row)*256 + kq*4);
    *(float4*)&As[row*260 + kq*4] = v;
  }

  for (int ch = 0; ch < nChunks; ch++) {
    int c0 = ch * 128;
    __syncthreads();                               // prior reads of Ws done / As staged
    for (int l = tid; l < 8192; l += 256) {        // 128 cols x 64 float4
      int c = l >> 6, kq = l & 63;
      float4 v = *(const float4*)(W + (size_t)(c0 + c)*256 + kq*4);
      uint2 p; p.x = packbf(v.x, v.y); p.y = packbf(v.z, v.w);
      *(uint2*)&Ws[c*130 + kq*2] = p;
    }
    __syncthreads();

    float acc[4][8];
#pragma unroll
    for (int rj = 0; rj < 4; rj++)
#pragma unroll
      for (int cj = 0; cj < 8; cj++)
        acc[rj][cj] = bias[c0 + tx + 16*cj];

#pragma unroll 2
    for (int kq = 0; kq < 64; kq++) {   // 4 k's per iteration
      float4 av[4];
#pragma unroll
      for (int rj = 0; rj < 4; rj++)
        av[rj] = *(const float4*)&As[(ty*4+rj)*260 + 4*kq];
#pragma unroll
      for (int cj = 0; cj < 8; cj++) {
        uint2 w2 = *(const uint2*)&Ws[(tx + 16*cj)*130 + 2*kq];
        float w0 = bflo(w2.x), w1 = bfhi(w2.x);
        float w2f = bflo(w2.y), w3 = bfhi(w2.y);
#pragma unroll
        for (int rj = 0; rj < 4; rj++)
          acc[rj][cj] += av[rj].x*w0 + av[rj].y*w1 + av[rj].z*w2f + av[rj].w*w3;
      }
    }
#pragma unroll
    for (int rj = 0; rj < 4; rj++)
#pragma unroll
      for (int cj = 0; cj < 8; cj++)
        C[(size_t)(r0 + ty*4 + rj)*N + c0 + tx + 16*cj] = acc[rj][cj];
  }
}

// ---------- K4: attention, one WG per (b, head) ----------
__global__ __launch_bounds__(256) void attn_kernel(
    const float* __restrict__ qkv, float* __restrict__ obuf)
{
  int b = blockIdx.x >> 3, h = blockIdx.x & 7;
  int tid = threadIdx.x;
  __shared__ unsigned short Kt[32][512];        // bf16 K^T [d][s]
  __shared__ __align__(16) float Vs[512][32];   // f32 V
  __shared__ unsigned short Sb[32][520];        // bf16 scores/probs, padded
  __shared__ float Qb[32][33];                  // f32 Q tile, padded

  for (int s = tid; s < 512; s += 256) {
    const float* kr = qkv + ((size_t)s * BB + b) * 768 + 256 + h * 32;
    const float* vr = kr + 256;
#pragma unroll
    for (int dq = 0; dq < 8; dq++) {
      float4 kv = *(const float4*)(kr + dq*4);
      float4 vv = *(const float4*)(vr + dq*4);
      Kt[dq*4+0][s] = f2bf(kv.x);
      Kt[dq*4+1][s] = f2bf(kv.y);
      Kt[dq*4+2][s] = f2bf(kv.z);
      Kt[dq*4+3][s] = f2bf(kv.w);
      *(float4*)&Vs[s][dq*4] = vv;
    }
  }

  int ty = tid >> 4, tx = tid & 15;   // scores roles: 2 rows x 8 cols
  int rr = tid >> 3, lg = tid & 7;    // softmax/PV roles
  int d0 = (tid & 7) * 4;

  for (int rb = 0; rb < 16; rb++) {
    int t0 = rb * 32;
    __syncthreads();   // K/V staged (rb=0) ; Qb/Sb free for rewrite
    for (int l = tid; l < 1024; l += 256) {
      int tr = l >> 5, d = l & 31;
      Qb[tr][d] = qkv[((size_t)(t0 + tr) * BB + b) * 768 + h * 32 + d] * 0.17677669529663687f;
    }
    __syncthreads();

    // scores
    for (int c4 = 0; c4 < 4; c4++) {
      int s0 = c4 * 128 + tx * 8;
      float acc0[8] = {0,0,0,0,0,0,0,0};
      float acc1[8] = {0,0,0,0,0,0,0,0};
#pragma unroll 8
      for (int d = 0; d < 32; d++) {
        float q0 = Qb[ty*2+0][d];
        float q1 = Qb[ty*2+1][d];
        uint4 kw = *(const uint4*)&Kt[d][s0];
        float k0 = bflo(kw.x), k1 = bfhi(kw.x);
        float k2 = bflo(kw.y), k3 = bfhi(kw.y);
        float k4 = bflo(kw.z), k5 = bfhi(kw.z);
        float k6 = bflo(kw.w), k7 = bfhi(kw.w);
        acc0[0]+=q0*k0; acc0[1]+=q0*k1; acc0[2]+=q0*k2; acc0[3]+=q0*k3;
        acc0[4]+=q0*k4; acc0[5]+=q0*k5; acc0[6]+=q0*k6; acc0[7]+=q0*k7;
        acc1[0]+=q1*k0; acc1[1]+=q1*k1; acc1[2]+=q1*k2; acc1[3]+=q1*k3;
        acc1[4]+=q1*k4; acc1[5]+=q1*k5; acc1[6]+=q1*k6; acc1[7]+=q1*k7;
      }
      unsigned* s0p = (unsigned*)&Sb[ty*2+0][s0];
      unsigned* s1p = (unsigned*)&Sb[ty*2+1][s0];
      s0p[0]=packbf(acc0[0],acc0[1]); s0p[1]=packbf(acc0[2],acc0[3]);
      s0p[2]=packbf(acc0[4],acc0[5]); s0p[3]=packbf(acc0[6],acc0[7]);
      s1p[0]=packbf(acc1[0],acc1[1]); s1p[1]=packbf(acc1[2],acc1[3]);
      s1p[2]=packbf(acc1[4],acc1[5]); s1p[3]=packbf(acc1[6],acc1[7]);
    }
    __syncthreads();

    // softmax over s (row rr, 8 lanes per row, strided columns)
    {
      unsigned* srow = (unsigned*)&Sb[rr][0];
      float vals[64];
      float m = -1e30f;
#pragma unroll
      for (int i = 0; i < 32; i++) {
        unsigned u = srow[lg + i*8];
        float va = bflo(u), vb = bfhi(u);
        vals[i*2] = va; vals[i*2+1] = vb;
        m = fmaxf(m, fmaxf(va, vb));
      }
      m = fmaxf(m, __shfl_xor(m, 1));
      m = fmaxf(m, __shfl_xor(m, 2));
      m = fmaxf(m, __shfl_xor(m, 4));
      float sum = 0.f;
#pragma unroll
      for (int i = 0; i < 64; i++) { float e = __expf(vals[i] - m); vals[i] = e; sum += e; }
      sum += __shfl_xor(sum, 1);
      sum += __shfl_xor(sum, 2);
      sum += __shfl_xor(sum, 4);
      float inv = 1.0f / sum;
#pragma unroll
      for (int i = 0; i < 32; i++)
        srow[lg + i*8] = packbf(vals[i*2]*inv, vals[i*2+1]*inv);
    }
    __syncthreads();

    // PV: o[rr][d0..d0+3]
    {
      float4 acc = make_float4(0,0,0,0);
#pragma unroll 4
      for (int s = 0; s < 512; s += 4) {
        uint2 pw = *(const uint2*)&Sb[rr][s];
        float p0 = bflo(pw.x), p1 = bfhi(pw.x), p2 = bflo(pw.y), p3 = bfhi(pw.y);
        float4 v0 = *(const float4*)&Vs[s+0][d0];
        float4 v1 = *(const float4*)&Vs[s+1][d0];
        float4 v2 = *(const float4*)&Vs[s+2][d0];
        float4 v3 = *(const float4*)&Vs[s+3][d0];
        acc.x += p0*v0.x + p1*v1.x + p2*v2.x + p3*v3.x;
        acc.y += p0*v0.y + p1*v1.y + p2*v2.y + p3*v3.y;
        acc.z += p0*v0.z + p1*v1.z + p2*v2.z + p3*v3.z;
        acc.w += p0*v0.w + p1*v1.w + p2*v2.w + p3*v3.w;
      }
      *(float4*)(obuf + ((size_t)(t0 + rr) * BB + b) * EE + h*32 + d0) = acc;
    }
  }
}

// ---------- K6: imputed = hc2 @ out_w.T + out_b ; blend ; write both outputs ----------
__global__ __launch_bounds__(256) void final_kernel(
    const float* __restrict__ A,      // hc2 [16384][256]
    const float* __restrict__ W,      // out_w [64][256]
    const float* __restrict__ bias,   // out_b [64]
    const float* __restrict__ x, const float* __restrict__ mask,
    float* __restrict__ out)          // [output | imputed], each [B][T][D]
{
  __shared__ float As[64*260];
  __shared__ unsigned Ws[64*130];
  int tid = threadIdx.x;
  int ty = tid >> 4, tx = tid & 15;
  int r0 = blockIdx.x * 64;

  for (int l = tid; l < 4096; l += 256) {
    int row = l >> 6, kq = l & 63;
    float4 v = *(const float4*)(A + (size_t)(r0 + row)*256 + kq*4);
    *(float4*)&As[row*260 + kq*4] = v;
  }
  for (int l = tid; l < 4096; l += 256) {
    int c = l >> 6, kq = l & 63;
    float4 v = *(const float4*)(W + (size_t)c*256 + kq*4);
    uint2 p; p.x = packbf(v.x, v.y); p.y = packbf(v.z, v.w);
    *(uint2*)&Ws[c*130 + kq*2] = p;
  }
  __syncthreads();

  float acc[4][4];
#pragma unroll
  for (int rj = 0; rj < 4; rj++)
#pragma unroll
    for (int cj = 0; cj < 4; cj++)
      acc[rj][cj] = bias[tx + 16*cj];

#pragma unroll 2
  for (int kq = 0; kq < 64; kq++) {
    float4 av[4];
#pragma unroll
    for (int rj = 0; rj < 4; rj++)
      av[rj] = *(const float4*)&As[(ty*4+rj)*260 + 4*kq];
#pragma unroll
    for (int cj = 0; cj < 4; cj++) {
      uint2 w2 = *(const uint2*)&Ws[(tx + 16*cj)*130 + 2*kq];
      float w0 = bflo(w2.x), w1 = bfhi(w2.x);
      float w2f = bflo(w2.y), w3 = bfhi(w2.y);
#pragma unroll
      for (int rj = 0; rj < 4; rj++)
        acc[rj][cj] += av[rj].x*w0 + av[rj].y*w1 + av[rj].z*w2f + av[rj].w*w3;
    }
  }

#pragma unroll
  for (int rj = 0; rj < 4; rj++) {
    int r = r0 + ty*4 + rj;
    int t = r >> 5, b = r & 31;
    size_t base = ((size_t)b * TT + t) * DD;
#pragma unroll
    for (int cj = 0; cj < 4; cj++) {
      int c = tx + 16*cj;
      float imp = acc[rj][cj];
      float xv = x[base + c], mv = mask[base + c];
      out[base + c] = xv*mv + imp*(1.0f - mv);
      out[(size_t)1048576 + base + c] = imp;
    }
  }
}

// ---------- launcher ----------
extern "C" void kernel_launch(void* const* d_in, const int* in_sizes, int n_in,
                              void* d_out, int out_size, void* d_ws, size_t ws_size,
                              hipStream_t stream) {
  const float* x     = (const float*)d_in[0];
  const float* mask  = (const float*)d_in[1];
  const float* fWi   = (const float*)d_in[2];
  const float* fbi   = (const float*)d_in[3];
  const float* fWh   = (const float*)d_in[4];
  const float* fbh   = (const float*)d_in[5];
  const float* bWi   = (const float*)d_in[6];
  const float* bbi   = (const float*)d_in[7];
  const float* bWh   = (const float*)d_in[8];
  const float* bbh   = (const float*)d_in[9];
  const float* aWin  = (const float*)d_in[10];
  const float* abin  = (const float*)d_in[11];
  const float* aWout = (const float*)d_in[12];
  const float* about = (const float*)d_in[13];
  const float* oW    = (const float*)d_in[14];
  const float* ob    = (const float*)d_in[15];
  float* out = (float*)d_out;
  float* ws  = (float*)d_ws;

  // workspace layout (f32 elems), with aliasing across pipeline phases:
  // [0, 12582912)        gi [16384][768]  -> later qkv [16384][768] -> later hc2 [16384][256]
  // [12582912, 16777216) hc  [16384][256] -> later obuf [16384][256]
  float* gi   = ws;
  float* hc   = ws + 12582912;
  float* qkv  = ws;
  float* obuf = ws + 12582912;
  float* hc2  = ws;

  gi_kernel<<<dim3(64, 2), 256, 0, stream>>>(x, mask, fWi, fbi, bWi, bbi, gi);
  scan_kernel<<<64, 256, 0, stream>>>(gi, fWh, fbh, bWh, bbh, hc);
  gemm_kernel<<<256, 256, 0, stream>>>(hc, aWin, abin, qkv, 768, 6);
  attn_kernel<<<256, 256, 0, stream>>>(qkv, obuf);
  gemm_kernel<<<256, 256, 0, stream>>>(obuf, aWout, about, hc2, 256, 2);
  final_kernel<<<256, 256, 0, stream>>>(hc2, oW, ob, x, mask, out);
}

// Round 7
// 1003.897 us; speedup vs baseline: 1.3017x; 1.3017x over previous
//
#include <hip/hip_runtime.h>

#define TT 512
#define BB 32
#define DD 64
#define HH 128
#define EE 256
#define NR 16384   // T*B rows

typedef _Float16 h2v __attribute__((ext_vector_type(2)));
typedef short bf16x8 __attribute__((ext_vector_type(8)));
typedef float f32x4 __attribute__((ext_vector_type(4)));

// ---------- helpers ----------
static __device__ __forceinline__ float bflo(unsigned u){ return __uint_as_float(u << 16); }
static __device__ __forceinline__ float bfhi(unsigned u){ return __uint_as_float(u & 0xFFFF0000u); }
static __device__ __forceinline__ unsigned short f2bf(float x){
  unsigned u = __float_as_uint(x);
  return (unsigned short)((u + 0x7FFFu + ((u >> 16) & 1u)) >> 16);  // RNE
}
static __device__ __forceinline__ unsigned packbf(float a, float b){
  return (unsigned)f2bf(a) | ((unsigned)f2bf(b) << 16);
}
static __device__ __forceinline__ float sigmoidf_(float x){
  return 1.0f / (1.0f + __expf(-x));
}
static __device__ __forceinline__ float tanhf_(float x){
  float e = __expf(2.0f * x);
  return 1.0f - 2.0f / (e + 1.0f);
}
static __device__ __forceinline__ unsigned packh2(float a, float b){
  h2v v; v.x = (_Float16)a; v.y = (_Float16)b;
  return __builtin_bit_cast(unsigned, v);
}
#define BCH(u) __builtin_bit_cast(h2v, (u))
#define DOT2(a, b, c) __builtin_amdgcn_fdot2((a), (b), (c), false)

// ---------- K1: gi[r][dir*384+j] = bi[j] + sum_d (x*mask)[r][d] * Wi[j][d] ----------
__global__ __launch_bounds__(256, 2) void gi_kernel(
    const float* __restrict__ x, const float* __restrict__ mask,
    const float* __restrict__ WiF, const float* __restrict__ biF,
    const float* __restrict__ WiB, const float* __restrict__ biB,
    float* __restrict__ gi)
{
  int r = blockIdx.x * 256 + threadIdx.x;
  int dir = blockIdx.y;
  const float* Wi = dir ? WiB : WiF;
  const float* bi = dir ? biB : biF;
  int t = r >> 5, b = r & 31;
  const float* xr = x + ((size_t)b * TT + t) * DD;
  const float* mr = mask + ((size_t)b * TT + t) * DD;
  float a[64];
#pragma unroll
  for (int i = 0; i < 16; i++) {
    float4 xv = *(const float4*)(xr + i*4);
    float4 mv = *(const float4*)(mr + i*4);
    a[i*4+0] = xv.x*mv.x; a[i*4+1] = xv.y*mv.y; a[i*4+2] = xv.z*mv.z; a[i*4+3] = xv.w*mv.w;
  }
  float* g = gi + (size_t)r * 768 + dir * 384;
  for (int j = 0; j < 384; j += 4) {
    float acc0 = bi[j+0], acc1 = bi[j+1], acc2 = bi[j+2], acc3 = bi[j+3];
    const float* w = Wi + (size_t)j * 64;
#pragma unroll
    for (int k = 0; k < 64; k++) {
      float av = a[k];
      acc0 += av * w[k];
      acc1 += av * w[64 + k];
      acc2 += av * w[128 + k];
      acc3 += av * w[192 + k];
    }
    *(float4*)(g + j) = make_float4(acc0, acc1, acc2, acc3);
  }
}

// ---------- K2: GRU scan (R5 version — best known, 454us). ----------
__global__ __launch_bounds__(512)
__attribute__((amdgpu_waves_per_eu(2, 2)))
void scan_kernel(
    const float* __restrict__ gi,      // [16384][768]
    const float* __restrict__ WhF, const float* __restrict__ bhF,
    const float* __restrict__ WhB, const float* __restrict__ bhB,
    float* __restrict__ hc)
{
  int dir = blockIdx.x >> 5;
  int b = blockIdx.x & 31;
  const float* Wh = dir ? WhB : WhF;
  const float* bh = dir ? bhB : bhF;
  int tid = threadIdx.x;
  int j1 = tid >> 1, h1 = tid & 1;
  int j2 = tid >> 2, q2 = tid & 3;

  __shared__ float h_s[128];                        // f32 state
  __shared__ __align__(16) unsigned hs16[68];       // f16-packed h: halves at u32 0 / 36
  __shared__ __align__(16) unsigned rh16[76];       // f16-packed rh: quarters at u32 0/20/40/60
  __shared__ float z_s[128];

  const float* wp1 = Wh + (size_t)j1 * 128 + h1 * 64;
#define LDA(n) unsigned A##n; { float2 t_ = *(const float2*)(wp1 + 2*(n)); A##n = packh2(t_.x, t_.y); }
  LDA(0) LDA(1) LDA(2) LDA(3) LDA(4) LDA(5) LDA(6) LDA(7)
  LDA(8) LDA(9) LDA(10) LDA(11) LDA(12) LDA(13) LDA(14) LDA(15)
  LDA(16) LDA(17) LDA(18) LDA(19) LDA(20) LDA(21) LDA(22) LDA(23)
  LDA(24) LDA(25) LDA(26) LDA(27) LDA(28) LDA(29) LDA(30) LDA(31)
#undef LDA
  const float* wp2 = Wh + (size_t)(256 + j2) * 128 + q2 * 32;
#define LDB(n) unsigned B##n; { float2 t_ = *(const float2*)(wp2 + 2*(n)); B##n = packh2(t_.x, t_.y); }
  LDB(0) LDB(1) LDB(2) LDB(3) LDB(4) LDB(5) LDB(6) LDB(7)
  LDB(8) LDB(9) LDB(10) LDB(11) LDB(12) LDB(13) LDB(14) LDB(15)
#undef LDB

  float bh1 = bh[j1];
  float bh2 = bh[256 + j2];

  if (tid < 128) h_s[tid] = 0.0f;
  if (tid < 68)  hs16[tid] = 0u;
  __syncthreads();

  size_t row0 = dir ? ((size_t)(TT-1)*BB + b) : (size_t)b;
  const float* grow = gi + row0 * 768 + dir * 384;
  long dstep = (dir ? -(long)BB : (long)BB) * 768;
  float gi1v = grow[j1];
  float gi2v = grow[256 + j2];

  for (int s = 0; s < TT; s++) {
#define PIN8(a,b_,c,d,e,f,g,hh) asm volatile("" : "+v"(a), "+v"(b_), "+v"(c), "+v"(d), "+v"(e), "+v"(f), "+v"(g), "+v"(hh));
    PIN8(A0,A1,A2,A3,A4,A5,A6,A7)
    PIN8(A8,A9,A10,A11,A12,A13,A14,A15)
    PIN8(A16,A17,A18,A19,A20,A21,A22,A23)
    PIN8(A24,A25,A26,A27,A28,A29,A30,A31)
    PIN8(B0,B1,B2,B3,B4,B5,B6,B7)
    PIN8(B8,B9,B10,B11,B12,B13,B14,B15)
#undef PIN8

    const float* gnext = grow + dstep;
    float gi1n = 0.f, gi2n = 0.f;
    if (s + 1 < TT) { gi1n = gnext[j1]; gi2n = gnext[256 + j2]; }

    float hold = h_s[j1 & 127];

    const unsigned* hp = hs16 + h1 * 36;
    float ya = 0.f, yb = 0.f, yc = 0.f, yd = 0.f;
#define S1(n, w0, w1, w2, w3) { uint4 hv = *(const uint4*)(hp + 4*(n)); \
    ya = DOT2(BCH(w0), BCH(hv.x), ya); yb = DOT2(BCH(w1), BCH(hv.y), yb); \
    yc = DOT2(BCH(w2), BCH(hv.z), yc); yd = DOT2(BCH(w3), BCH(hv.w), yd); }
    S1(0, A0,A1,A2,A3)     S1(1, A4,A5,A6,A7)
    S1(2, A8,A9,A10,A11)   S1(3, A12,A13,A14,A15)
    S1(4, A16,A17,A18,A19) S1(5, A20,A21,A22,A23)
    S1(6, A24,A25,A26,A27) S1(7, A28,A29,A30,A31)
#undef S1
    float y = (ya + yb) + (yc + yd);
    y += __shfl_xor(y, 1);
    float sg = sigmoidf_(gi1v + y + bh1);
    float rhv = sg * hold;
    float rhp = __shfl_xor(rhv, 2);
    if ((tid & 3) == 0 && j1 < 128) {
      int pi = j1 >> 1;
      rh16[(pi & 15) + 20 * (pi >> 4)] = packh2(rhv, rhp);
    }
    if (h1 == 0 && j1 >= 128) z_s[j1 - 128] = sg;
    __syncthreads();   // barrier A

    const unsigned* rp = rh16 + q2 * 20;
    float ca = 0.f, cb = 0.f, cc = 0.f, cd = 0.f;
#define S2(n, w0, w1, w2, w3) { uint4 rv = *(const uint4*)(rp + 4*(n)); \
    ca = DOT2(BCH(w0), BCH(rv.x), ca); cb = DOT2(BCH(w1), BCH(rv.y), cb); \
    cc = DOT2(BCH(w2), BCH(rv.z), cc); cd = DOT2(BCH(w3), BCH(rv.w), cd); }
    S2(0, B0,B1,B2,B3)   S2(1, B4,B5,B6,B7)
    S2(2, B8,B9,B10,B11) S2(3, B12,B13,B14,B15)
#undef S2
    float y2 = (ca + cb) + (cc + cd);
    y2 += __shfl_xor(y2, 1);
    y2 += __shfl_xor(y2, 2);
    float nn = tanhf_(gi2v + y2 + bh2);
    float zv = z_s[j2];
    float hv_ = h_s[j2];
    float hn = nn + zv * (hv_ - nn);
    float hnp = __shfl_xor(hn, 4);
    if ((tid & 3) == 0) {
      h_s[j2] = hn;
      int t = dir ? (TT - 1 - s) : s;
      hc[((size_t)t * BB + b) * EE + dir * HH + j2] = hn;
    }
    if ((tid & 7) == 0) {
      int pi = j2 >> 1;
      hs16[(pi & 31) + 36 * (j2 >> 6)] = packh2(hn, hnp);
    }
    __syncthreads();   // barrier B
    gi1v = gi1n; gi2v = gi2n;
    grow = gnext;
  }
}

// ---------- K3/K5: MFMA GEMM. C[r][c] = bias[c] + sum_k A[r][k]*W[c][k], K=256 ----------
// 64-row M-tile per WG (4 waves x 16 rows), N chunked by 64, bf16 fragments.
// LDS stride 264 bf16 = 528B -> row-to-row bank shift of 4, max 2-way aliasing (free).
// mfma_f32_16x16x32_bf16: A-frag row = lane&15, k = (lane>>4)*8+e ; D: col=lane&15,
// row=(lane>>4)*4+reg (m89-verified). Both frags share k-enumeration -> permutation-safe.
__global__ __launch_bounds__(256) void mfma_gemm_kernel(
    const float* __restrict__ A, const float* __restrict__ W,
    const float* __restrict__ bias, float* __restrict__ C,
    int N)
{
  __shared__ unsigned short As[64*264];
  __shared__ unsigned short Ws[64*264];
  int tid = threadIdx.x;
  int r0 = blockIdx.x * 64;
  int lane = tid & 63;
  int w = tid >> 6;          // wave id -> rows w*16 .. w*16+15
  int lr = lane & 15;
  int lk = lane >> 4;

  // stage A (64 rows x 256 k) as bf16, once
#pragma unroll
  for (int it = 0; it < 16; ++it) {
    int l = tid + it*256;
    int row = l >> 6, kq = l & 63;
    float4 v = *(const float4*)(A + (size_t)(r0+row)*256 + kq*4);
    unsigned* dst = (unsigned*)&As[row*264 + kq*4];
    dst[0] = packbf(v.x, v.y);
    dst[1] = packbf(v.z, v.w);
  }

  const unsigned short* arow = &As[(w*16 + lr)*264 + lk*8];
  const unsigned short* wrow0 = &Ws[(0*16 + lr)*264 + lk*8];
  const unsigned short* wrow1 = &Ws[(1*16 + lr)*264 + lk*8];
  const unsigned short* wrow2 = &Ws[(2*16 + lr)*264 + lk*8];
  const unsigned short* wrow3 = &Ws[(3*16 + lr)*264 + lk*8];

  int nChunks = N >> 6;
  for (int ch = 0; ch < nChunks; ++ch) {
    int c0 = ch << 6;
    __syncthreads();          // As ready (ch=0) / prior chunk's Ws reads done
#pragma unroll
    for (int it = 0; it < 16; ++it) {
      int l = tid + it*256;
      int row = l >> 6, kq = l & 63;
      float4 v = *(const float4*)(W + (size_t)(c0+row)*256 + kq*4);
      unsigned* dst = (unsigned*)&Ws[row*264 + kq*4];
      dst[0] = packbf(v.x, v.y);
      dst[1] = packbf(v.z, v.w);
    }
    __syncthreads();

    float b0 = bias[c0 + lr], b1 = bias[c0 + 16 + lr];
    float b2 = bias[c0 + 32 + lr], b3 = bias[c0 + 48 + lr];
    f32x4 acc0 = {b0, b0, b0, b0};
    f32x4 acc1 = {b1, b1, b1, b1};
    f32x4 acc2 = {b2, b2, b2, b2};
    f32x4 acc3 = {b3, b3, b3, b3};

#pragma unroll
    for (int ks = 0; ks < 8; ++ks) {
      bf16x8 a  = *(const bf16x8*)(arow  + ks*32);
      bf16x8 q0 = *(const bf16x8*)(wrow0 + ks*32);
      bf16x8 q1 = *(const bf16x8*)(wrow1 + ks*32);
      bf16x8 q2 = *(const bf16x8*)(wrow2 + ks*32);
      bf16x8 q3 = *(const bf16x8*)(wrow3 + ks*32);
      acc0 = __builtin_amdgcn_mfma_f32_16x16x32_bf16(a, q0, acc0, 0, 0, 0);
      acc1 = __builtin_amdgcn_mfma_f32_16x16x32_bf16(a, q1, acc1, 0, 0, 0);
      acc2 = __builtin_amdgcn_mfma_f32_16x16x32_bf16(a, q2, acc2, 0, 0, 0);
      acc3 = __builtin_amdgcn_mfma_f32_16x16x32_bf16(a, q3, acc3, 0, 0, 0);
    }

#pragma unroll
    for (int j = 0; j < 4; ++j) {
      int row = r0 + w*16 + lk*4 + j;
      float* cp = C + (size_t)row * N + c0 + lr;
      cp[0]  = acc0[j];
      cp[16] = acc1[j];
      cp[32] = acc2[j];
      cp[48] = acc3[j];
    }
  }
}

// ---------- K4: attention, one WG per (b, head) ----------
__global__ __launch_bounds__(256) void attn_kernel(
    const float* __restrict__ qkv, float* __restrict__ obuf)
{
  int b = blockIdx.x >> 3, h = blockIdx.x & 7;
  int tid = threadIdx.x;
  __shared__ unsigned short Kt[32][512];        // bf16 K^T [d][s]
  __shared__ __align__(16) float Vs[512][32];   // f32 V
  __shared__ unsigned short Sb[32][520];        // bf16 scores/probs, padded
  __shared__ float Qb[32][33];                  // f32 Q tile, padded

  for (int s = tid; s < 512; s += 256) {
    const float* kr = qkv + ((size_t)s * BB + b) * 768 + 256 + h * 32;
    const float* vr = kr + 256;
#pragma unroll
    for (int dq = 0; dq < 8; dq++) {
      float4 kv = *(const float4*)(kr + dq*4);
      float4 vv = *(const float4*)(vr + dq*4);
      Kt[dq*4+0][s] = f2bf(kv.x);
      Kt[dq*4+1][s] = f2bf(kv.y);
      Kt[dq*4+2][s] = f2bf(kv.z);
      Kt[dq*4+3][s] = f2bf(kv.w);
      *(float4*)&Vs[s][dq*4] = vv;
    }
  }

  int ty = tid >> 4, tx = tid & 15;   // scores roles: 2 rows x 8 cols
  int rr = tid >> 3, lg = tid & 7;    // softmax/PV roles
  int d0 = (tid & 7) * 4;

  for (int rb = 0; rb < 16; rb++) {
    int t0 = rb * 32;
    __syncthreads();
    for (int l = tid; l < 1024; l += 256) {
      int tr = l >> 5, d = l & 31;
      Qb[tr][d] = qkv[((size_t)(t0 + tr) * BB + b) * 768 + h * 32 + d] * 0.17677669529663687f;
    }
    __syncthreads();

    // scores
    for (int c4 = 0; c4 < 4; c4++) {
      int s0 = c4 * 128 + tx * 8;
      float acc0[8] = {0,0,0,0,0,0,0,0};
      float acc1[8] = {0,0,0,0,0,0,0,0};
#pragma unroll 8
      for (int d = 0; d < 32; d++) {
        float q0 = Qb[ty*2+0][d];
        float q1 = Qb[ty*2+1][d];
        uint4 kw = *(const uint4*)&Kt[d][s0];
        float k0 = bflo(kw.x), k1 = bfhi(kw.x);
        float k2 = bflo(kw.y), k3 = bfhi(kw.y);
        float k4 = bflo(kw.z), k5 = bfhi(kw.z);
        float k6 = bflo(kw.w), k7 = bfhi(kw.w);
        acc0[0]+=q0*k0; acc0[1]+=q0*k1; acc0[2]+=q0*k2; acc0[3]+=q0*k3;
        acc0[4]+=q0*k4; acc0[5]+=q0*k5; acc0[6]+=q0*k6; acc0[7]+=q0*k7;
        acc1[0]+=q1*k0; acc1[1]+=q1*k1; acc1[2]+=q1*k2; acc1[3]+=q1*k3;
        acc1[4]+=q1*k4; acc1[5]+=q1*k5; acc1[6]+=q1*k6; acc1[7]+=q1*k7;
      }
      unsigned* s0p = (unsigned*)&Sb[ty*2+0][s0];
      unsigned* s1p = (unsigned*)&Sb[ty*2+1][s0];
      s0p[0]=packbf(acc0[0],acc0[1]); s0p[1]=packbf(acc0[2],acc0[3]);
      s0p[2]=packbf(acc0[4],acc0[5]); s0p[3]=packbf(acc0[6],acc0[7]);
      s1p[0]=packbf(acc1[0],acc1[1]); s1p[1]=packbf(acc1[2],acc1[3]);
      s1p[2]=packbf(acc1[4],acc1[5]); s1p[3]=packbf(acc1[6],acc1[7]);
    }
    __syncthreads();

    // softmax
    {
      unsigned* srow = (unsigned*)&Sb[rr][0];
      float vals[64];
      float m = -1e30f;
#pragma unroll
      for (int i = 0; i < 32; i++) {
        unsigned u = srow[lg + i*8];
        float va = bflo(u), vb = bfhi(u);
        vals[i*2] = va; vals[i*2+1] = vb;
        m = fmaxf(m, fmaxf(va, vb));
      }
      m = fmaxf(m, __shfl_xor(m, 1));
      m = fmaxf(m, __shfl_xor(m, 2));
      m = fmaxf(m, __shfl_xor(m, 4));
      float sum = 0.f;
#pragma unroll
      for (int i = 0; i < 64; i++) { float e = __expf(vals[i] - m); vals[i] = e; sum += e; }
      sum += __shfl_xor(sum, 1);
      sum += __shfl_xor(sum, 2);
      sum += __shfl_xor(sum, 4);
      float inv = 1.0f / sum;
#pragma unroll
      for (int i = 0; i < 32; i++)
        srow[lg + i*8] = packbf(vals[i*2]*inv, vals[i*2+1]*inv);
    }
    __syncthreads();

    // PV
    {
      float4 acc = make_float4(0,0,0,0);
#pragma unroll 4
      for (int s = 0; s < 512; s += 4) {
        uint2 pw = *(const uint2*)&Sb[rr][s];
        float p0 = bflo(pw.x), p1 = bfhi(pw.x), p2 = bflo(pw.y), p3 = bfhi(pw.y);
        float4 v0 = *(const float4*)&Vs[s+0][d0];
        float4 v1 = *(const float4*)&Vs[s+1][d0];
        float4 v2 = *(const float4*)&Vs[s+2][d0];
        float4 v3 = *(const float4*)&Vs[s+3][d0];
        acc.x += p0*v0.x + p1*v1.x + p2*v2.x + p3*v3.x;
        acc.y += p0*v0.y + p1*v1.y + p2*v2.y + p3*v3.y;
        acc.z += p0*v0.z + p1*v1.z + p2*v2.z + p3*v3.z;
        acc.w += p0*v0.w + p1*v1.w + p2*v2.w + p3*v3.w;
      }
      *(float4*)(obuf + ((size_t)(t0 + rr) * BB + b) * EE + h*32 + d0) = acc;
    }
  }
}

// ---------- K6: imputed = hc2 @ out_w.T + out_b ; blend ; write both outputs ----------
__global__ __launch_bounds__(256) void final_kernel(
    const float* __restrict__ A,      // hc2 [16384][256]
    const float* __restrict__ W,      // out_w [64][256]
    const float* __restrict__ bias,   // out_b [64]
    const float* __restrict__ x, const float* __restrict__ mask,
    float* __restrict__ out)          // [output | imputed], each [B][T][D]
{
  __shared__ float As[64*260];
  __shared__ unsigned Ws[64*130];
  int tid = threadIdx.x;
  int ty = tid >> 4, tx = tid & 15;
  int r0 = blockIdx.x * 64;

  for (int l = tid; l < 4096; l += 256) {
    int row = l >> 6, kq = l & 63;
    float4 v = *(const float4*)(A + (size_t)(r0 + row)*256 + kq*4);
    *(float4*)&As[row*260 + kq*4] = v;
  }
  for (int l = tid; l < 4096; l += 256) {
    int c = l >> 6, kq = l & 63;
    float4 v = *(const float4*)(W + (size_t)c*256 + kq*4);
    uint2 p; p.x = packbf(v.x, v.y); p.y = packbf(v.z, v.w);
    *(uint2*)&Ws[c*130 + kq*2] = p;
  }
  __syncthreads();

  float acc[4][4];
#pragma unroll
  for (int rj = 0; rj < 4; rj++)
#pragma unroll
    for (int cj = 0; cj < 4; cj++)
      acc[rj][cj] = bias[tx + 16*cj];

#pragma unroll 2
  for (int kq = 0; kq < 64; kq++) {
    float4 av[4];
#pragma unroll
    for (int rj = 0; rj < 4; rj++)
      av[rj] = *(const float4*)&As[(ty*4+rj)*260 + 4*kq];
#pragma unroll
    for (int cj = 0; cj < 4; cj++) {
      uint2 w2 = *(const uint2*)&Ws[(tx + 16*cj)*130 + 2*kq];
      float w0 = bflo(w2.x), w1 = bfhi(w2.x);
      float w2f = bflo(w2.y), w3 = bfhi(w2.y);
#pragma unroll
      for (int rj = 0; rj < 4; rj++)
        acc[rj][cj] += av[rj].x*w0 + av[rj].y*w1 + av[rj].z*w2f + av[rj].w*w3;
    }
  }

#pragma unroll
  for (int rj = 0; rj < 4; rj++) {
    int r = r0 + ty*4 + rj;
    int t = r >> 5, b = r & 31;
    size_t base = ((size_t)b * TT + t) * DD;
#pragma unroll
    for (int cj = 0; cj < 4; cj++) {
      int c = tx + 16*cj;
      float imp = acc[rj][cj];
      float xv = x[base + c], mv = mask[base + c];
      out[base + c] = xv*mv + imp*(1.0f - mv);
      out[(size_t)1048576 + base + c] = imp;
    }
  }
}

// ---------- launcher ----------
extern "C" void kernel_launch(void* const* d_in, const int* in_sizes, int n_in,
                              void* d_out, int out_size, void* d_ws, size_t ws_size,
                              hipStream_t stream) {
  const float* x     = (const float*)d_in[0];
  const float* mask  = (const float*)d_in[1];
  const float* fWi   = (const float*)d_in[2];
  const float* fbi   = (const float*)d_in[3];
  const float* fWh   = (const float*)d_in[4];
  const float* fbh   = (const float*)d_in[5];
  const float* bWi   = (const float*)d_in[6];
  const float* bbi   = (const float*)d_in[7];
  const float* bWh   = (const float*)d_in[8];
  const float* bbh   = (const float*)d_in[9];
  const float* aWin  = (const float*)d_in[10];
  const float* abin  = (const float*)d_in[11];
  const float* aWout = (const float*)d_in[12];
  const float* about = (const float*)d_in[13];
  const float* oW    = (const float*)d_in[14];
  const float* ob    = (const float*)d_in[15];
  float* out = (float*)d_out;
  float* ws  = (float*)d_ws;

  // workspace layout (f32 elems), aliased across phases:
  // [0, 12582912)        gi [16384][768] -> qkv [16384][768] -> hc2 [16384][256]
  // [12582912, 16777216) hc [16384][256] -> obuf [16384][256]
  float* gi   = ws;
  float* hc   = ws + 12582912;
  float* qkv  = ws;
  float* obuf = ws + 12582912;
  float* hc2  = ws;

  gi_kernel<<<dim3(64, 2), 256, 0, stream>>>(x, mask, fWi, fbi, bWi, bbi, gi);
  scan_kernel<<<64, 512, 0, stream>>>(gi, fWh, fbh, bWh, bbh, hc);
  mfma_gemm_kernel<<<256, 256, 0, stream>>>(hc, aWin, abin, qkv, 768);
  attn_kernel<<<256, 256, 0, stream>>>(qkv, obuf);
  mfma_gemm_kernel<<<256, 256, 0, stream>>>(obuf, aWout, about, hc2, 256);
  final_kernel<<<256, 256, 0, stream>>>(hc2, oW, ob, x, mask, out);
}

// Round 8
// 992.841 us; speedup vs baseline: 1.3162x; 1.0111x over previous
//
#include <hip/hip_runtime.h>

#define TT 512
#define BB 32
#define DD 64
#define HH 128
#define EE 256
#define NR 16384   // T*B rows

typedef _Float16 h2v __attribute__((ext_vector_type(2)));
typedef short bf16x8 __attribute__((ext_vector_type(8)));
typedef float f32x4 __attribute__((ext_vector_type(4)));

// ---------- helpers ----------
static __device__ __forceinline__ float bflo(unsigned u){ return __uint_as_float(u << 16); }
static __device__ __forceinline__ float bfhi(unsigned u){ return __uint_as_float(u & 0xFFFF0000u); }
static __device__ __forceinline__ unsigned short f2bf(float x){
  unsigned u = __float_as_uint(x);
  return (unsigned short)((u + 0x7FFFu + ((u >> 16) & 1u)) >> 16);  // RNE
}
static __device__ __forceinline__ unsigned packbf(float a, float b){
  return (unsigned)f2bf(a) | ((unsigned)f2bf(b) << 16);
}
static __device__ __forceinline__ float sigmoidf_(float x){
  return 1.0f / (1.0f + __expf(-x));
}
static __device__ __forceinline__ float tanhf_(float x){
  float e = __expf(2.0f * x);
  return 1.0f - 2.0f / (e + 1.0f);
}
static __device__ __forceinline__ unsigned packh2(float a, float b){
  h2v v; v.x = (_Float16)a; v.y = (_Float16)b;
  return __builtin_bit_cast(unsigned, v);
}
#define BCH(u) __builtin_bit_cast(h2v, (u))
#define DOT2(a, b, c) __builtin_amdgcn_fdot2((a), (b), (c), false)
// Barrier that drains ONLY LDS (lgkmcnt), leaving global loads/stores in
// flight. __syncthreads() emits s_waitcnt vmcnt(0) lgkmcnt(0) which drags
// the gi-prefetch L2 latency + hc-store retire into the critical path
// twice per step. LDS visibility across waves only needs lgkmcnt(0).
#define LGKM_BARRIER() asm volatile("s_waitcnt lgkmcnt(0)\n\ts_barrier" ::: "memory")

// ---------- K1: gi[r][dir*384+j] = bi[j] + sum_d (x*mask)[r][d] * Wi[j][d] ----------
__global__ __launch_bounds__(256, 2) void gi_kernel(
    const float* __restrict__ x, const float* __restrict__ mask,
    const float* __restrict__ WiF, const float* __restrict__ biF,
    const float* __restrict__ WiB, const float* __restrict__ biB,
    float* __restrict__ gi)
{
  int r = blockIdx.x * 256 + threadIdx.x;
  int dir = blockIdx.y;
  const float* Wi = dir ? WiB : WiF;
  const float* bi = dir ? biB : biF;
  int t = r >> 5, b = r & 31;
  const float* xr = x + ((size_t)b * TT + t) * DD;
  const float* mr = mask + ((size_t)b * TT + t) * DD;
  float a[64];
#pragma unroll
  for (int i = 0; i < 16; i++) {
    float4 xv = *(const float4*)(xr + i*4);
    float4 mv = *(const float4*)(mr + i*4);
    a[i*4+0] = xv.x*mv.x; a[i*4+1] = xv.y*mv.y; a[i*4+2] = xv.z*mv.z; a[i*4+3] = xv.w*mv.w;
  }
  float* g = gi + (size_t)r * 768 + dir * 384;
  for (int j = 0; j < 384; j += 4) {
    float acc0 = bi[j+0], acc1 = bi[j+1], acc2 = bi[j+2], acc3 = bi[j+3];
    const float* w = Wi + (size_t)j * 64;
#pragma unroll
    for (int k = 0; k < 64; k++) {
      float av = a[k];
      acc0 += av * w[k];
      acc1 += av * w[64 + k];
      acc2 += av * w[128 + k];
      acc3 += av * w[192 + k];
    }
    *(float4*)(g + j) = make_float4(acc0, acc1, acc2, acc3);
  }
}

// ---------- K2: GRU scan (R5 structure + lgkm-only barriers). ----------
__global__ __launch_bounds__(512)
__attribute__((amdgpu_waves_per_eu(2, 2)))
void scan_kernel(
    const float* __restrict__ gi,      // [16384][768]
    const float* __restrict__ WhF, const float* __restrict__ bhF,
    const float* __restrict__ WhB, const float* __restrict__ bhB,
    float* __restrict__ hc)
{
  int dir = blockIdx.x >> 5;
  int b = blockIdx.x & 31;
  const float* Wh = dir ? WhB : WhF;
  const float* bh = dir ? bhB : bhF;
  int tid = threadIdx.x;
  int j1 = tid >> 1, h1 = tid & 1;
  int j2 = tid >> 2, q2 = tid & 3;

  __shared__ float h_s[128];                        // f32 state
  __shared__ __align__(16) unsigned hs16[68];       // f16-packed h: halves at u32 0 / 36
  __shared__ __align__(16) unsigned rh16[76];       // f16-packed rh: quarters at u32 0/20/40/60
  __shared__ float z_s[128];

  const float* wp1 = Wh + (size_t)j1 * 128 + h1 * 64;
#define LDA(n) unsigned A##n; { float2 t_ = *(const float2*)(wp1 + 2*(n)); A##n = packh2(t_.x, t_.y); }
  LDA(0) LDA(1) LDA(2) LDA(3) LDA(4) LDA(5) LDA(6) LDA(7)
  LDA(8) LDA(9) LDA(10) LDA(11) LDA(12) LDA(13) LDA(14) LDA(15)
  LDA(16) LDA(17) LDA(18) LDA(19) LDA(20) LDA(21) LDA(22) LDA(23)
  LDA(24) LDA(25) LDA(26) LDA(27) LDA(28) LDA(29) LDA(30) LDA(31)
#undef LDA
  const float* wp2 = Wh + (size_t)(256 + j2) * 128 + q2 * 32;
#define LDB(n) unsigned B##n; { float2 t_ = *(const float2*)(wp2 + 2*(n)); B##n = packh2(t_.x, t_.y); }
  LDB(0) LDB(1) LDB(2) LDB(3) LDB(4) LDB(5) LDB(6) LDB(7)
  LDB(8) LDB(9) LDB(10) LDB(11) LDB(12) LDB(13) LDB(14) LDB(15)
#undef LDB

  float bh1 = bh[j1];
  float bh2 = bh[256 + j2];

  if (tid < 128) h_s[tid] = 0.0f;
  if (tid < 68)  hs16[tid] = 0u;
  __syncthreads();

  size_t row0 = dir ? ((size_t)(TT-1)*BB + b) : (size_t)b;
  const float* grow = gi + row0 * 768 + dir * 384;
  long dstep = (dir ? -(long)BB : (long)BB) * 768;
  float gi1v = grow[j1];
  float gi2v = grow[256 + j2];

  for (int s = 0; s < TT; s++) {
#define PIN8(a,b_,c,d,e,f,g,hh) asm volatile("" : "+v"(a), "+v"(b_), "+v"(c), "+v"(d), "+v"(e), "+v"(f), "+v"(g), "+v"(hh));
    PIN8(A0,A1,A2,A3,A4,A5,A6,A7)
    PIN8(A8,A9,A10,A11,A12,A13,A14,A15)
    PIN8(A16,A17,A18,A19,A20,A21,A22,A23)
    PIN8(A24,A25,A26,A27,A28,A29,A30,A31)
    PIN8(B0,B1,B2,B3,B4,B5,B6,B7)
    PIN8(B8,B9,B10,B11,B12,B13,B14,B15)
#undef PIN8

    const float* gnext = grow + dstep;
    float gi1n = 0.f, gi2n = 0.f;
    if (s + 1 < TT) { gi1n = gnext[j1]; gi2n = gnext[256 + j2]; }

    float hold = h_s[j1 & 127];

    const unsigned* hp = hs16 + h1 * 36;
    float ya = 0.f, yb = 0.f, yc = 0.f, yd = 0.f;
#define S1(n, w0, w1, w2, w3) { uint4 hv = *(const uint4*)(hp + 4*(n)); \
    ya = DOT2(BCH(w0), BCH(hv.x), ya); yb = DOT2(BCH(w1), BCH(hv.y), yb); \
    yc = DOT2(BCH(w2), BCH(hv.z), yc); yd = DOT2(BCH(w3), BCH(hv.w), yd); }
    S1(0, A0,A1,A2,A3)     S1(1, A4,A5,A6,A7)
    S1(2, A8,A9,A10,A11)   S1(3, A12,A13,A14,A15)
    S1(4, A16,A17,A18,A19) S1(5, A20,A21,A22,A23)
    S1(6, A24,A25,A26,A27) S1(7, A28,A29,A30,A31)
#undef S1
    float y = (ya + yb) + (yc + yd);
    y += __shfl_xor(y, 1);
    float sg = sigmoidf_(gi1v + y + bh1);
    float rhv = sg * hold;
    float rhp = __shfl_xor(rhv, 2);
    if ((tid & 3) == 0 && j1 < 128) {
      int pi = j1 >> 1;
      rh16[(pi & 15) + 20 * (pi >> 4)] = packh2(rhv, rhp);
    }
    if (h1 == 0 && j1 >= 128) z_s[j1 - 128] = sg;
    LGKM_BARRIER();   // barrier A: rh/z visible (LDS only; gi loads stay in flight)

    const unsigned* rp = rh16 + q2 * 20;
    float ca = 0.f, cb = 0.f, cc = 0.f, cd = 0.f;
#define S2(n, w0, w1, w2, w3) { uint4 rv = *(const uint4*)(rp + 4*(n)); \
    ca = DOT2(BCH(w0), BCH(rv.x), ca); cb = DOT2(BCH(w1), BCH(rv.y), cb); \
    cc = DOT2(BCH(w2), BCH(rv.z), cc); cd = DOT2(BCH(w3), BCH(rv.w), cd); }
    S2(0, B0,B1,B2,B3)   S2(1, B4,B5,B6,B7)
    S2(2, B8,B9,B10,B11) S2(3, B12,B13,B14,B15)
#undef S2
    float y2 = (ca + cb) + (cc + cd);
    y2 += __shfl_xor(y2, 1);
    y2 += __shfl_xor(y2, 2);
    float nn = tanhf_(gi2v + y2 + bh2);
    float zv = z_s[j2];
    float hv_ = h_s[j2];
    float hn = nn + zv * (hv_ - nn);
    float hnp = __shfl_xor(hn, 4);
    if ((tid & 3) == 0) {
      h_s[j2] = hn;
      int t = dir ? (TT - 1 - s) : s;
      hc[((size_t)t * BB + b) * EE + dir * HH + j2] = hn;   // store stays in flight
    }
    if ((tid & 7) == 0) {
      int pi = j2 >> 1;
      hs16[(pi & 31) + 36 * (j2 >> 6)] = packh2(hn, hnp);
    }
    LGKM_BARRIER();   // barrier B: h visible (LDS only; hc store not drained)
    gi1v = gi1n; gi2v = gi2n;
    grow = gnext;
  }
}

// ---------- K3/K5: MFMA GEMM. C[r][c] = bias[c] + sum_k A[r][k]*W[c][k], K=256 ----------
__global__ __launch_bounds__(256) void mfma_gemm_kernel(
    const float* __restrict__ A, const float* __restrict__ W,
    const float* __restrict__ bias, float* __restrict__ C,
    int N)
{
  __shared__ unsigned short As[64*264];
  __shared__ unsigned short Ws[64*264];
  int tid = threadIdx.x;
  int r0 = blockIdx.x * 64;
  int lane = tid & 63;
  int w = tid >> 6;          // wave id -> rows w*16 .. w*16+15
  int lr = lane & 15;
  int lk = lane >> 4;

  // stage A (64 rows x 256 k) as bf16, once
#pragma unroll
  for (int it = 0; it < 16; ++it) {
    int l = tid + it*256;
    int row = l >> 6, kq = l & 63;
    float4 v = *(const float4*)(A + (size_t)(r0+row)*256 + kq*4);
    unsigned* dst = (unsigned*)&As[row*264 + kq*4];
    dst[0] = packbf(v.x, v.y);
    dst[1] = packbf(v.z, v.w);
  }

  const unsigned short* arow = &As[(w*16 + lr)*264 + lk*8];
  const unsigned short* wrow0 = &Ws[(0*16 + lr)*264 + lk*8];
  const unsigned short* wrow1 = &Ws[(1*16 + lr)*264 + lk*8];
  const unsigned short* wrow2 = &Ws[(2*16 + lr)*264 + lk*8];
  const unsigned short* wrow3 = &Ws[(3*16 + lr)*264 + lk*8];

  int nChunks = N >> 6;
  for (int ch = 0; ch < nChunks; ++ch) {
    int c0 = ch << 6;
    __syncthreads();          // As ready (ch=0) / prior chunk's Ws reads done
#pragma unroll
    for (int it = 0; it < 16; ++it) {
      int l = tid + it*256;
      int row = l >> 6, kq = l & 63;
      float4 v = *(const float4*)(W + (size_t)(c0+row)*256 + kq*4);
      unsigned* dst = (unsigned*)&Ws[row*264 + kq*4];
      dst[0] = packbf(v.x, v.y);
      dst[1] = packbf(v.z, v.w);
    }
    __syncthreads();

    float b0 = bias[c0 + lr], b1 = bias[c0 + 16 + lr];
    float b2 = bias[c0 + 32 + lr], b3 = bias[c0 + 48 + lr];
    f32x4 acc0 = {b0, b0, b0, b0};
    f32x4 acc1 = {b1, b1, b1, b1};
    f32x4 acc2 = {b2, b2, b2, b2};
    f32x4 acc3 = {b3, b3, b3, b3};

#pragma unroll
    for (int ks = 0; ks < 8; ++ks) {
      bf16x8 a  = *(const bf16x8*)(arow  + ks*32);
      bf16x8 q0 = *(const bf16x8*)(wrow0 + ks*32);
      bf16x8 q1 = *(const bf16x8*)(wrow1 + ks*32);
      bf16x8 q2 = *(const bf16x8*)(wrow2 + ks*32);
      bf16x8 q3 = *(const bf16x8*)(wrow3 + ks*32);
      acc0 = __builtin_amdgcn_mfma_f32_16x16x32_bf16(a, q0, acc0, 0, 0, 0);
      acc1 = __builtin_amdgcn_mfma_f32_16x16x32_bf16(a, q1, acc1, 0, 0, 0);
      acc2 = __builtin_amdgcn_mfma_f32_16x16x32_bf16(a, q2, acc2, 0, 0, 0);
      acc3 = __builtin_amdgcn_mfma_f32_16x16x32_bf16(a, q3, acc3, 0, 0, 0);
    }

#pragma unroll
    for (int j = 0; j < 4; ++j) {
      int row = r0 + w*16 + lk*4 + j;
      float* cp = C + (size_t)row * N + c0 + lr;
      cp[0]  = acc0[j];
      cp[16] = acc1[j];
      cp[32] = acc2[j];
      cp[48] = acc3[j];
    }
  }
}

// ---------- K4: attention, one WG per (b, head) ----------
__global__ __launch_bounds__(256) void attn_kernel(
    const float* __restrict__ qkv, float* __restrict__ obuf)
{
  int b = blockIdx.x >> 3, h = blockIdx.x & 7;
  int tid = threadIdx.x;
  __shared__ unsigned short Kt[32][512];        // bf16 K^T [d][s]
  __shared__ __align__(16) float Vs[512][32];   // f32 V
  __shared__ unsigned short Sb[32][520];        // bf16 scores/probs, padded
  __shared__ float Qb[32][33];                  // f32 Q tile, padded

  for (int s = tid; s < 512; s += 256) {
    const float* kr = qkv + ((size_t)s * BB + b) * 768 + 256 + h * 32;
    const float* vr = kr + 256;
#pragma unroll
    for (int dq = 0; dq < 8; dq++) {
      float4 kv = *(const float4*)(kr + dq*4);
      float4 vv = *(const float4*)(vr + dq*4);
      Kt[dq*4+0][s] = f2bf(kv.x);
      Kt[dq*4+1][s] = f2bf(kv.y);
      Kt[dq*4+2][s] = f2bf(kv.z);
      Kt[dq*4+3][s] = f2bf(kv.w);
      *(float4*)&Vs[s][dq*4] = vv;
    }
  }

  int ty = tid >> 4, tx = tid & 15;   // scores roles: 2 rows x 8 cols
  int rr = tid >> 3, lg = tid & 7;    // softmax/PV roles
  int d0 = (tid & 7) * 4;

  for (int rb = 0; rb < 16; rb++) {
    int t0 = rb * 32;
    __syncthreads();
    for (int l = tid; l < 1024; l += 256) {
      int tr = l >> 5, d = l & 31;
      Qb[tr][d] = qkv[((size_t)(t0 + tr) * BB + b) * 768 + h * 32 + d] * 0.17677669529663687f;
    }
    __syncthreads();

    // scores
    for (int c4 = 0; c4 < 4; c4++) {
      int s0 = c4 * 128 + tx * 8;
      float acc0[8] = {0,0,0,0,0,0,0,0};
      float acc1[8] = {0,0,0,0,0,0,0,0};
#pragma unroll 8
      for (int d = 0; d < 32; d++) {
        float q0 = Qb[ty*2+0][d];
        float q1 = Qb[ty*2+1][d];
        uint4 kw = *(const uint4*)&Kt[d][s0];
        float k0 = bflo(kw.x), k1 = bfhi(kw.x);
        float k2 = bflo(kw.y), k3 = bfhi(kw.y);
        float k4 = bflo(kw.z), k5 = bfhi(kw.z);
        float k6 = bflo(kw.w), k7 = bfhi(kw.w);
        acc0[0]+=q0*k0; acc0[1]+=q0*k1; acc0[2]+=q0*k2; acc0[3]+=q0*k3;
        acc0[4]+=q0*k4; acc0[5]+=q0*k5; acc0[6]+=q0*k6; acc0[7]+=q0*k7;
        acc1[0]+=q1*k0; acc1[1]+=q1*k1; acc1[2]+=q1*k2; acc1[3]+=q1*k3;
        acc1[4]+=q1*k4; acc1[5]+=q1*k5; acc1[6]+=q1*k6; acc1[7]+=q1*k7;
      }
      unsigned* s0p = (unsigned*)&Sb[ty*2+0][s0];
      unsigned* s1p = (unsigned*)&Sb[ty*2+1][s0];
      s0p[0]=packbf(acc0[0],acc0[1]); s0p[1]=packbf(acc0[2],acc0[3]);
      s0p[2]=packbf(acc0[4],acc0[5]); s0p[3]=packbf(acc0[6],acc0[7]);
      s1p[0]=packbf(acc1[0],acc1[1]); s1p[1]=packbf(acc1[2],acc1[3]);
      s1p[2]=packbf(acc1[4],acc1[5]); s1p[3]=packbf(acc1[6],acc1[7]);
    }
    __syncthreads();

    // softmax
    {
      unsigned* srow = (unsigned*)&Sb[rr][0];
      float vals[64];
      float m = -1e30f;
#pragma unroll
      for (int i = 0; i < 32; i++) {
        unsigned u = srow[lg + i*8];
        float va = bflo(u), vb = bfhi(u);
        vals[i*2] = va; vals[i*2+1] = vb;
        m = fmaxf(m, fmaxf(va, vb));
      }
      m = fmaxf(m, __shfl_xor(m, 1));
      m = fmaxf(m, __shfl_xor(m, 2));
      m = fmaxf(m, __shfl_xor(m, 4));
      float sum = 0.f;
#pragma unroll
      for (int i = 0; i < 64; i++) { float e = __expf(vals[i] - m); vals[i] = e; sum += e; }
      sum += __shfl_xor(sum, 1);
      sum += __shfl_xor(sum, 2);
      sum += __shfl_xor(sum, 4);
      float inv = 1.0f / sum;
#pragma unroll
      for (int i = 0; i < 32; i++)
        srow[lg + i*8] = packbf(vals[i*2]*inv, vals[i*2+1]*inv);
    }
    __syncthreads();

    // PV
    {
      float4 acc = make_float4(0,0,0,0);
#pragma unroll 4
      for (int s = 0; s < 512; s += 4) {
        uint2 pw = *(const uint2*)&Sb[rr][s];
        float p0 = bflo(pw.x), p1 = bfhi(pw.x), p2 = bflo(pw.y), p3 = bfhi(pw.y);
        float4 v0 = *(const float4*)&Vs[s+0][d0];
        float4 v1 = *(const float4*)&Vs[s+1][d0];
        float4 v2 = *(const float4*)&Vs[s+2][d0];
        float4 v3 = *(const float4*)&Vs[s+3][d0];
        acc.x += p0*v0.x + p1*v1.x + p2*v2.x + p3*v3.x;
        acc.y += p0*v0.y + p1*v1.y + p2*v2.y + p3*v3.y;
        acc.z += p0*v0.z + p1*v1.z + p2*v2.z + p3*v3.z;
        acc.w += p0*v0.w + p1*v1.w + p2*v2.w + p3*v3.w;
      }
      *(float4*)(obuf + ((size_t)(t0 + rr) * BB + b) * EE + h*32 + d0) = acc;
    }
  }
}

// ---------- K6: imputed = hc2 @ out_w.T + out_b ; blend ; write both outputs ----------
__global__ __launch_bounds__(256) void final_kernel(
    const float* __restrict__ A,      // hc2 [16384][256]
    const float* __restrict__ W,      // out_w [64][256]
    const float* __restrict__ bias,   // out_b [64]
    const float* __restrict__ x, const float* __restrict__ mask,
    float* __restrict__ out)          // [output | imputed], each [B][T][D]
{
  __shared__ float As[64*260];
  __shared__ unsigned Ws[64*130];
  int tid = threadIdx.x;
  int ty = tid >> 4, tx = tid & 15;
  int r0 = blockIdx.x * 64;

  for (int l = tid; l < 4096; l += 256) {
    int row = l >> 6, kq = l & 63;
    float4 v = *(const float4*)(A + (size_t)(r0 + row)*256 + kq*4);
    *(float4*)&As[row*260 + kq*4] = v;
  }
  for (int l = tid; l < 4096; l += 256) {
    int c = l >> 6, kq = l & 63;
    float4 v = *(const float4*)(W + (size_t)c*256 + kq*4);
    uint2 p; p.x = packbf(v.x, v.y); p.y = packbf(v.z, v.w);
    *(uint2*)&Ws[c*130 + kq*2] = p;
  }
  __syncthreads();

  float acc[4][4];
#pragma unroll
  for (int rj = 0; rj < 4; rj++)
#pragma unroll
    for (int cj = 0; cj < 4; cj++)
      acc[rj][cj] = bias[tx + 16*cj];

#pragma unroll 2
  for (int kq = 0; kq < 64; kq++) {
    float4 av[4];
#pragma unroll
    for (int rj = 0; rj < 4; rj++)
      av[rj] = *(const float4*)&As[(ty*4+rj)*260 + 4*kq];
#pragma unroll
    for (int cj = 0; cj < 4; cj++) {
      uint2 w2 = *(const uint2*)&Ws[(tx + 16*cj)*130 + 2*kq];
      float w0 = bflo(w2.x), w1 = bfhi(w2.x);
      float w2f = bflo(w2.y), w3 = bfhi(w2.y);
#pragma unroll
      for (int rj = 0; rj < 4; rj++)
        acc[rj][cj] += av[rj].x*w0 + av[rj].y*w1 + av[rj].z*w2f + av[rj].w*w3;
    }
  }

#pragma unroll
  for (int rj = 0; rj < 4; rj++) {
    int r = r0 + ty*4 + rj;
    int t = r >> 5, b = r & 31;
    size_t base = ((size_t)b * TT + t) * DD;
#pragma unroll
    for (int cj = 0; cj < 4; cj++) {
      int c = tx + 16*cj;
      float imp = acc[rj][cj];
      float xv = x[base + c], mv = mask[base + c];
      out[base + c] = xv*mv + imp*(1.0f - mv);
      out[(size_t)1048576 + base + c] = imp;
    }
  }
}

// ---------- launcher ----------
extern "C" void kernel_launch(void* const* d_in, const int* in_sizes, int n_in,
                              void* d_out, int out_size, void* d_ws, size_t ws_size,
                              hipStream_t stream) {
  const float* x     = (const float*)d_in[0];
  const float* mask  = (const float*)d_in[1];
  const float* fWi   = (const float*)d_in[2];
  const float* fbi   = (const float*)d_in[3];
  const float* fWh   = (const float*)d_in[4];
  const float* fbh   = (const float*)d_in[5];
  const float* bWi   = (const float*)d_in[6];
  const float* bbi   = (const float*)d_in[7];
  const float* bWh   = (const float*)d_in[8];
  const float* bbh   = (const float*)d_in[9];
  const float* aWin  = (const float*)d_in[10];
  const float* abin  = (const float*)d_in[11];
  const float* aWout = (const float*)d_in[12];
  const float* about = (const float*)d_in[13];
  const float* oW    = (const float*)d_in[14];
  const float* ob    = (const float*)d_in[15];
  float* out = (float*)d_out;
  float* ws  = (float*)d_ws;

  // workspace layout (f32 elems), aliased across phases:
  // [0, 12582912)        gi [16384][768] -> qkv [16384][768] -> hc2 [16384][256]
  // [12582912, 16777216) hc [16384][256] -> obuf [16384][256]
  float* gi   = ws;
  float* hc   = ws + 12582912;
  float* qkv  = ws;
  float* obuf = ws + 12582912;
  float* hc2  = ws;

  gi_kernel<<<dim3(64, 2), 256, 0, stream>>>(x, mask, fWi, fbi, bWi, bbi, gi);
  scan_kernel<<<64, 512, 0, stream>>>(gi, fWh, fbh, bWh, bbh, hc);
  mfma_gemm_kernel<<<256, 256, 0, stream>>>(hc, aWin, abin, qkv, 768);
  attn_kernel<<<256, 256, 0, stream>>>(qkv, obuf);
  mfma_gemm_kernel<<<256, 256, 0, stream>>>(obuf, aWout, about, hc2, 256);
  final_kernel<<<256, 256, 0, stream>>>(hc2, oW, ob, x, mask, out);
}

// Round 9
// 783.389 us; speedup vs baseline: 1.6681x; 1.2674x over previous
//
#include <hip/hip_runtime.h>

#define TT 512
#define BB 32
#define DD 64
#define HH 128
#define EE 256
#define NR 16384   // T*B rows

typedef _Float16 h2v __attribute__((ext_vector_type(2)));
typedef short bf16x8 __attribute__((ext_vector_type(8)));
typedef float f32x4 __attribute__((ext_vector_type(4)));

// ---------- helpers ----------
static __device__ __forceinline__ float bflo(unsigned u){ return __uint_as_float(u << 16); }
static __device__ __forceinline__ float bfhi(unsigned u){ return __uint_as_float(u & 0xFFFF0000u); }
static __device__ __forceinline__ unsigned short f2bf(float x){
  unsigned u = __float_as_uint(x);
  return (unsigned short)((u + 0x7FFFu + ((u >> 16) & 1u)) >> 16);  // RNE
}
static __device__ __forceinline__ unsigned packbf(float a, float b){
  return (unsigned)f2bf(a) | ((unsigned)f2bf(b) << 16);
}
static __device__ __forceinline__ float sigmoidf_(float x){
  return 1.0f / (1.0f + __expf(-x));
}
static __device__ __forceinline__ float tanhf_(float x){
  float e = __expf(2.0f * x);
  return 1.0f - 2.0f / (e + 1.0f);
}
static __device__ __forceinline__ unsigned packh2(float a, float b){
  h2v v; v.x = (_Float16)a; v.y = (_Float16)b;
  return __builtin_bit_cast(unsigned, v);
}
#define BCH(u) __builtin_bit_cast(h2v, (u))
#define DOT2(a, b, c) __builtin_amdgcn_fdot2((a), (b), (c), false)
// LDS-only barrier: don't drain vmcnt (gi prefetch / hc stores stay in flight)
#define LGKM_BARRIER() asm volatile("s_waitcnt lgkmcnt(0)\n\ts_barrier" ::: "memory")

// ---------- K1: gi[r][dir*384+j] = bi[j] + sum_d (x*mask)[r][d] * Wi[j][d] ----------
__global__ __launch_bounds__(256, 2) void gi_kernel(
    const float* __restrict__ x, const float* __restrict__ mask,
    const float* __restrict__ WiF, const float* __restrict__ biF,
    const float* __restrict__ WiB, const float* __restrict__ biB,
    float* __restrict__ gi)
{
  int r = blockIdx.x * 256 + threadIdx.x;
  int dir = blockIdx.y;
  const float* Wi = dir ? WiB : WiF;
  const float* bi = dir ? biB : biF;
  int t = r >> 5, b = r & 31;
  const float* xr = x + ((size_t)b * TT + t) * DD;
  const float* mr = mask + ((size_t)b * TT + t) * DD;
  float a[64];
#pragma unroll
  for (int i = 0; i < 16; i++) {
    float4 xv = *(const float4*)(xr + i*4);
    float4 mv = *(const float4*)(mr + i*4);
    a[i*4+0] = xv.x*mv.x; a[i*4+1] = xv.y*mv.y; a[i*4+2] = xv.z*mv.z; a[i*4+3] = xv.w*mv.w;
  }
  float* g = gi + (size_t)r * 768 + dir * 384;
  for (int j = 0; j < 384; j += 4) {
    float acc0 = bi[j+0], acc1 = bi[j+1], acc2 = bi[j+2], acc3 = bi[j+3];
    const float* w = Wi + (size_t)j * 64;
#pragma unroll
    for (int k = 0; k < 64; k++) {
      float av = a[k];
      acc0 += av * w[k];
      acc1 += av * w[64 + k];
      acc2 += av * w[128 + k];
      acc3 += av * w[192 + k];
    }
    *(float4*)(g + j) = make_float4(acc0, acc1, acc2, acc3);
  }
}

// ---------- K2: GRU scan. 256 threads (4 waves), R5 dataflow. ----------
// stage1: thread tid owns rz output tid (full 128-dot, 64 pinned u32 weights).
// stage2: pair (j2=tid>>1, h2=tid&1) owns n output j2, 64-dot half (32 u32).
// Fewer waves -> narrower barrier, less skew; LDS reads are uniform broadcasts.
__global__ __launch_bounds__(256)
__attribute__((amdgpu_waves_per_eu(1, 1)))
void scan_kernel(
    const float* __restrict__ gi,      // [16384][768]
    const float* __restrict__ WhF, const float* __restrict__ bhF,
    const float* __restrict__ WhB, const float* __restrict__ bhB,
    float* __restrict__ hc)
{
  int dir = blockIdx.x >> 5;
  int b = blockIdx.x & 31;
  const float* Wh = dir ? WhB : WhF;
  const float* bh = dir ? bhB : bhF;
  int tid = threadIdx.x;
  int j2 = tid >> 1, h2 = tid & 1;

  __shared__ float h_s[128];                        // f32 state
  __shared__ __align__(16) unsigned hs16[68];       // f16 h pairs: halves at 0 / 36
  __shared__ __align__(16) unsigned rh16[76];       // f16 rh pairs: quarters at 0/20/40/60
  __shared__ float z_s[128];

  // stage-1 weights: full row tid (128 f32 -> 64 packed u32), k-order matches hs16 layout
  const float* wp1 = Wh + (size_t)tid * 128;
#define LDA(n) unsigned A##n = packh2(wp1[2*(n)], wp1[2*(n)+1]);
  LDA(0) LDA(1) LDA(2) LDA(3) LDA(4) LDA(5) LDA(6) LDA(7)
  LDA(8) LDA(9) LDA(10) LDA(11) LDA(12) LDA(13) LDA(14) LDA(15)
  LDA(16) LDA(17) LDA(18) LDA(19) LDA(20) LDA(21) LDA(22) LDA(23)
  LDA(24) LDA(25) LDA(26) LDA(27) LDA(28) LDA(29) LDA(30) LDA(31)
  LDA(32) LDA(33) LDA(34) LDA(35) LDA(36) LDA(37) LDA(38) LDA(39)
  LDA(40) LDA(41) LDA(42) LDA(43) LDA(44) LDA(45) LDA(46) LDA(47)
  LDA(48) LDA(49) LDA(50) LDA(51) LDA(52) LDA(53) LDA(54) LDA(55)
  LDA(56) LDA(57) LDA(58) LDA(59) LDA(60) LDA(61) LDA(62) LDA(63)
#undef LDA
  // stage-2 weights: half-row of Wh_n row (256+j2)
  const float* wp2 = Wh + (size_t)(256 + j2) * 128 + h2 * 64;
#define LDB(n) unsigned B##n = packh2(wp2[2*(n)], wp2[2*(n)+1]);
  LDB(0) LDB(1) LDB(2) LDB(3) LDB(4) LDB(5) LDB(6) LDB(7)
  LDB(8) LDB(9) LDB(10) LDB(11) LDB(12) LDB(13) LDB(14) LDB(15)
  LDB(16) LDB(17) LDB(18) LDB(19) LDB(20) LDB(21) LDB(22) LDB(23)
  LDB(24) LDB(25) LDB(26) LDB(27) LDB(28) LDB(29) LDB(30) LDB(31)
#undef LDB

  float bh1 = bh[tid];
  float bh2 = bh[256 + j2];

  if (tid < 128) h_s[tid] = 0.0f;
  if (tid < 68)  hs16[tid] = 0u;
  __syncthreads();

  size_t row0 = dir ? ((size_t)(TT-1)*BB + b) : (size_t)b;
  const float* grow = gi + row0 * 768 + dir * 384;
  long dstep = (dir ? -(long)BB : (long)BB) * 768;
  float gi1v = grow[tid];
  float gi2v = grow[256 + j2];

  for (int s = 0; s < TT; s++) {
#define PIN8(a,b_,c,d,e,f,g,hh) asm volatile("" : "+v"(a), "+v"(b_), "+v"(c), "+v"(d), "+v"(e), "+v"(f), "+v"(g), "+v"(hh));
    PIN8(A0,A1,A2,A3,A4,A5,A6,A7)
    PIN8(A8,A9,A10,A11,A12,A13,A14,A15)
    PIN8(A16,A17,A18,A19,A20,A21,A22,A23)
    PIN8(A24,A25,A26,A27,A28,A29,A30,A31)
    PIN8(A32,A33,A34,A35,A36,A37,A38,A39)
    PIN8(A40,A41,A42,A43,A44,A45,A46,A47)
    PIN8(A48,A49,A50,A51,A52,A53,A54,A55)
    PIN8(A56,A57,A58,A59,A60,A61,A62,A63)
    PIN8(B0,B1,B2,B3,B4,B5,B6,B7)
    PIN8(B8,B9,B10,B11,B12,B13,B14,B15)
    PIN8(B16,B17,B18,B19,B20,B21,B22,B23)
    PIN8(B24,B25,B26,B27,B28,B29,B30,B31)
#undef PIN8

    const float* gnext = grow + dstep;
    float gi1n = 0.f, gi2n = 0.f;
    if (s + 1 < TT) { gi1n = gnext[tid]; gi2n = gnext[256 + j2]; }

    float hold = h_s[tid & 127];

    // stage 1: full 128-dot (64 dot2), h halves at hs16+0 / hs16+36 (uniform broadcasts)
    const unsigned* hp0 = hs16;
    const unsigned* hp1 = hs16 + 36;
    float ya = 0.f, yb = 0.f, yc = 0.f, yd = 0.f;
#define S1(n, base, w0, w1, w2, w3) { uint4 hv = *(const uint4*)((base) + 4*(n)); \
    ya = DOT2(BCH(w0), BCH(hv.x), ya); yb = DOT2(BCH(w1), BCH(hv.y), yb); \
    yc = DOT2(BCH(w2), BCH(hv.z), yc); yd = DOT2(BCH(w3), BCH(hv.w), yd); }
    S1(0, hp0, A0,A1,A2,A3)     S1(1, hp0, A4,A5,A6,A7)
    S1(2, hp0, A8,A9,A10,A11)   S1(3, hp0, A12,A13,A14,A15)
    S1(4, hp0, A16,A17,A18,A19) S1(5, hp0, A20,A21,A22,A23)
    S1(6, hp0, A24,A25,A26,A27) S1(7, hp0, A28,A29,A30,A31)
    S1(0, hp1, A32,A33,A34,A35) S1(1, hp1, A36,A37,A38,A39)
    S1(2, hp1, A40,A41,A42,A43) S1(3, hp1, A44,A45,A46,A47)
    S1(4, hp1, A48,A49,A50,A51) S1(5, hp1, A52,A53,A54,A55)
    S1(6, hp1, A56,A57,A58,A59) S1(7, hp1, A60,A61,A62,A63)
#undef S1
    float y = (ya + yb) + (yc + yd);
    float sg = sigmoidf_(gi1v + y + bh1);
    float rhv = sg * hold;
    float rhp = __shfl_xor(rhv, 1);          // partner output tid+1
    if (tid < 128) {
      if ((tid & 1) == 0) {
        int pi = tid >> 1;                   // pair 0..63
        rh16[(pi & 15) + 20 * (pi >> 4)] = packh2(rhv, rhp);
      }
    } else {
      z_s[tid - 128] = sg;
    }
    LGKM_BARRIER();   // barrier A: rh/z visible

    // stage 2: 64-dot half (32 dot2): quarters at h2*40 and h2*40+20
    const unsigned* rp0 = rh16 + h2 * 40;
    const unsigned* rp1 = rp0 + 20;
    float ca = 0.f, cb = 0.f, cc = 0.f, cd = 0.f;
#define S2(n, base, w0, w1, w2, w3) { uint4 rv = *(const uint4*)((base) + 4*(n)); \
    ca = DOT2(BCH(w0), BCH(rv.x), ca); cb = DOT2(BCH(w1), BCH(rv.y), cb); \
    cc = DOT2(BCH(w2), BCH(rv.z), cc); cd = DOT2(BCH(w3), BCH(rv.w), cd); }
    S2(0, rp0, B0,B1,B2,B3)     S2(1, rp0, B4,B5,B6,B7)
    S2(2, rp0, B8,B9,B10,B11)   S2(3, rp0, B12,B13,B14,B15)
    S2(0, rp1, B16,B17,B18,B19) S2(1, rp1, B20,B21,B22,B23)
    S2(2, rp1, B24,B25,B26,B27) S2(3, rp1, B28,B29,B30,B31)
#undef S2
    float y2 = (ca + cb) + (cc + cd);
    y2 += __shfl_xor(y2, 1);
    float nn = tanhf_(gi2v + y2 + bh2);
    float zv = z_s[j2];
    float hv_ = h_s[j2];
    float hn = nn + zv * (hv_ - nn);
    float hnp = __shfl_xor(hn, 2);           // partner output j2+1 (thread tid+2)
    if (h2 == 0) {
      h_s[j2] = hn;
      int t = dir ? (TT - 1 - s) : s;
      hc[((size_t)t * BB + b) * EE + dir * HH + j2] = hn;
    }
    if ((tid & 3) == 0) {
      int pi = tid >> 2;                     // h pair j2>>1 = 0..63
      hs16[(pi & 31) + 36 * (j2 >> 6)] = packh2(hn, hnp);
    }
    LGKM_BARRIER();   // barrier B: h visible
    gi1v = gi1n; gi2v = gi2n;
    grow = gnext;
  }
}

// ---------- K3/K5: MFMA GEMM. C[r][c] = bias[c] + sum_k A[r][k]*W[c][k], K=256 ----------
__global__ __launch_bounds__(256) void mfma_gemm_kernel(
    const float* __restrict__ A, const float* __restrict__ W,
    const float* __restrict__ bias, float* __restrict__ C,
    int N)
{
  __shared__ unsigned short As[64*264];
  __shared__ unsigned short Ws[64*264];
  int tid = threadIdx.x;
  int r0 = blockIdx.x * 64;
  int lane = tid & 63;
  int w = tid >> 6;          // wave id -> rows w*16 .. w*16+15
  int lr = lane & 15;
  int lk = lane >> 4;

#pragma unroll
  for (int it = 0; it < 16; ++it) {
    int l = tid + it*256;
    int row = l >> 6, kq = l & 63;
    float4 v = *(const float4*)(A + (size_t)(r0+row)*256 + kq*4);
    unsigned* dst = (unsigned*)&As[row*264 + kq*4];
    dst[0] = packbf(v.x, v.y);
    dst[1] = packbf(v.z, v.w);
  }

  const unsigned short* arow = &As[(w*16 + lr)*264 + lk*8];
  const unsigned short* wrow0 = &Ws[(0*16 + lr)*264 + lk*8];
  const unsigned short* wrow1 = &Ws[(1*16 + lr)*264 + lk*8];
  const unsigned short* wrow2 = &Ws[(2*16 + lr)*264 + lk*8];
  const unsigned short* wrow3 = &Ws[(3*16 + lr)*264 + lk*8];

  int nChunks = N >> 6;
  for (int ch = 0; ch < nChunks; ++ch) {
    int c0 = ch << 6;
    __syncthreads();
#pragma unroll
    for (int it = 0; it < 16; ++it) {
      int l = tid + it*256;
      int row = l >> 6, kq = l & 63;
      float4 v = *(const float4*)(W + (size_t)(c0+row)*256 + kq*4);
      unsigned* dst = (unsigned*)&Ws[row*264 + kq*4];
      dst[0] = packbf(v.x, v.y);
      dst[1] = packbf(v.z, v.w);
    }
    __syncthreads();

    float b0 = bias[c0 + lr], b1 = bias[c0 + 16 + lr];
    float b2 = bias[c0 + 32 + lr], b3 = bias[c0 + 48 + lr];
    f32x4 acc0 = {b0, b0, b0, b0};
    f32x4 acc1 = {b1, b1, b1, b1};
    f32x4 acc2 = {b2, b2, b2, b2};
    f32x4 acc3 = {b3, b3, b3, b3};

#pragma unroll
    for (int ks = 0; ks < 8; ++ks) {
      bf16x8 a  = *(const bf16x8*)(arow  + ks*32);
      bf16x8 q0 = *(const bf16x8*)(wrow0 + ks*32);
      bf16x8 q1 = *(const bf16x8*)(wrow1 + ks*32);
      bf16x8 q2 = *(const bf16x8*)(wrow2 + ks*32);
      bf16x8 q3 = *(const bf16x8*)(wrow3 + ks*32);
      acc0 = __builtin_amdgcn_mfma_f32_16x16x32_bf16(a, q0, acc0, 0, 0, 0);
      acc1 = __builtin_amdgcn_mfma_f32_16x16x32_bf16(a, q1, acc1, 0, 0, 0);
      acc2 = __builtin_amdgcn_mfma_f32_16x16x32_bf16(a, q2, acc2, 0, 0, 0);
      acc3 = __builtin_amdgcn_mfma_f32_16x16x32_bf16(a, q3, acc3, 0, 0, 0);
    }

#pragma unroll
    for (int j = 0; j < 4; ++j) {
      int row = r0 + w*16 + lk*4 + j;
      float* cp = C + (size_t)row * N + c0 + lr;
      cp[0]  = acc0[j];
      cp[16] = acc1[j];
      cp[32] = acc2[j];
      cp[48] = acc3[j];
    }
  }
}

// ---------- K4: MFMA attention, one WG per (b, head). ----------
// Layouts verified by the working mfma_gemm: A row=lane&15 k=(lane>>4)*8+e ;
// D col=lane&15 row=(lane>>4)*4+reg. s-permutation s'=(s&15)*32+(s>>4) applied
// identically to P columns and V^T rows -> contraction invariant, contiguous
// P writes. All LDS rows are wave-private -> no per-pass barriers.
__global__ __launch_bounds__(256, 1) void attn_mfma_kernel(
    const float* __restrict__ qkv, float* __restrict__ obuf)
{
  int b = blockIdx.x >> 3, h = blockIdx.x & 7;
  int tid = threadIdx.x;
  int lane = tid & 63;
  int w = tid >> 6;
  int lr = lane & 15, lk = lane >> 4;

  __shared__ unsigned short Ks[512*40];   // K rows [s][40] bf16 (80B stride)
  __shared__ unsigned short Vt[32*520];   // V^T [d][s'] bf16
  __shared__ unsigned short Sb[64*520];   // P [qrow][s'] bf16 (wave-private rows)
  __shared__ unsigned short Qs[64*40];    // Q tile (wave-private rows)

  // stage K and V^T (once)
  for (int l = tid; l < 4096; l += 256) {
    int s = l >> 3, dq = l & 7;
    const float* kr = qkv + ((size_t)s*BB + b)*768 + 256 + h*32 + dq*4;
    float4 kv = *(const float4*)kr;
    unsigned* kd = (unsigned*)&Ks[s*40 + dq*4];
    kd[0] = packbf(kv.x, kv.y);
    kd[1] = packbf(kv.z, kv.w);
    float4 vv = *(const float4*)(kr + 256);
    int sp = ((s & 15) << 5) + (s >> 4);
    Vt[(dq*4+0)*520 + sp] = f2bf(vv.x);
    Vt[(dq*4+1)*520 + sp] = f2bf(vv.y);
    Vt[(dq*4+2)*520 + sp] = f2bf(vv.z);
    Vt[(dq*4+3)*520 + sp] = f2bf(vv.w);
  }
  __syncthreads();

  const float SCL = 0.17677669529663687f;   // 1/sqrt(32)

  for (int p = 0; p < 8; ++p) {
    int q0 = p*64 + w*16;                   // this wave's 16 q rows
    // stage own Q rows (16 x 32, scaled)
#pragma unroll
    for (int i = 0; i < 2; ++i) {
      int l = lane + i*64;                  // 0..127
      int row = l >> 3, dq = l & 7;
      const float* qr = qkv + ((size_t)(q0+row)*BB + b)*768 + h*32 + dq*4;
      float4 qv = *(const float4*)qr;
      unsigned* qd = (unsigned*)&Qs[(w*16+row)*40 + dq*4];
      qd[0] = packbf(qv.x*SCL, qv.y*SCL);
      qd[1] = packbf(qv.z*SCL, qv.w*SCL);
    }
    // QK^T: 32 s-tiles, one mfma each (K=32 = full head dim)
    bf16x8 a = *(const bf16x8*)&Qs[(w*16+lr)*40 + lk*8];
    f32x4 st[32];
#pragma unroll
    for (int t = 0; t < 32; ++t) {
      bf16x8 kb = *(const bf16x8*)&Ks[(t*16+lr)*40 + lk*8];
      f32x4 z = {0.f, 0.f, 0.f, 0.f};
      st[t] = __builtin_amdgcn_mfma_f32_16x16x32_bf16(a, kb, z, 0, 0, 0);
    }
    // softmax per row (row = lk*4+j; cols distributed over 16 lr-lanes x 32 tiles)
    float inv[4];
#pragma unroll
    for (int j = 0; j < 4; ++j) {
      float m = -3e38f;
#pragma unroll
      for (int t = 0; t < 32; ++t) m = fmaxf(m, st[t][j]);
      m = fmaxf(m, __shfl_xor(m, 1));
      m = fmaxf(m, __shfl_xor(m, 2));
      m = fmaxf(m, __shfl_xor(m, 4));
      m = fmaxf(m, __shfl_xor(m, 8));
      float sum = 0.f;
#pragma unroll
      for (int t = 0; t < 32; ++t) { float e = __expf(st[t][j] - m); st[t][j] = e; sum += e; }
      sum += __shfl_xor(sum, 1);
      sum += __shfl_xor(sum, 2);
      sum += __shfl_xor(sum, 4);
      sum += __shfl_xor(sum, 8);
      inv[j] = 1.0f / sum;
    }
    // write P (bf16) at s' = lr*32 + t : contiguous 64B per row per lane
#pragma unroll
    for (int j = 0; j < 4; ++j) {
      unsigned pk[16];
#pragma unroll
      for (int i = 0; i < 16; ++i)
        pk[i] = packbf(st[2*i][j]*inv[j], st[2*i+1][j]*inv[j]);
      uint4* dst = (uint4*)&Sb[(w*16 + lk*4 + j)*520 + lr*32];
      dst[0] = make_uint4(pk[0], pk[1], pk[2], pk[3]);
      dst[1] = make_uint4(pk[4], pk[5], pk[6], pk[7]);
      dst[2] = make_uint4(pk[8], pk[9], pk[10], pk[11]);
      dst[3] = make_uint4(pk[12], pk[13], pk[14], pk[15]);
    }
    // PV: O[16 x 32] = P[16 x 512] @ V[512 x 32] over permuted k
    f32x4 o0 = {0.f,0.f,0.f,0.f}, o1 = {0.f,0.f,0.f,0.f};
#pragma unroll
    for (int kt = 0; kt < 16; ++kt) {
      bf16x8 pa = *(const bf16x8*)&Sb[(w*16 + lr)*520 + kt*32 + lk*8];
      bf16x8 v0 = *(const bf16x8*)&Vt[(lr)*520 + kt*32 + lk*8];
      bf16x8 v1 = *(const bf16x8*)&Vt[(16 + lr)*520 + kt*32 + lk*8];
      o0 = __builtin_amdgcn_mfma_f32_16x16x32_bf16(pa, v0, o0, 0, 0, 0);
      o1 = __builtin_amdgcn_mfma_f32_16x16x32_bf16(pa, v1, o1, 0, 0, 0);
    }
    // store O
#pragma unroll
    for (int j = 0; j < 4; ++j) {
      int q = q0 + lk*4 + j;
      float* op = obuf + ((size_t)q*BB + b)*EE + h*32;
      op[lr]      = o0[j];
      op[16 + lr] = o1[j];
    }
  }
}

// ---------- K6: imputed = hc2 @ out_w.T + out_b ; blend ; write both outputs ----------
__global__ __launch_bounds__(256) void final_kernel(
    const float* __restrict__ A,      // hc2 [16384][256]
    const float* __restrict__ W,      // out_w [64][256]
    const float* __restrict__ bias,   // out_b [64]
    const float* __restrict__ x, const float* __restrict__ mask,
    float* __restrict__ out)          // [output | imputed], each [B][T][D]
{
  __shared__ float As[64*260];
  __shared__ unsigned Ws[64*130];
  int tid = threadIdx.x;
  int ty = tid >> 4, tx = tid & 15;
  int r0 = blockIdx.x * 64;

  for (int l = tid; l < 4096; l += 256) {
    int row = l >> 6, kq = l & 63;
    float4 v = *(const float4*)(A + (size_t)(r0 + row)*256 + kq*4);
    *(float4*)&As[row*260 + kq*4] = v;
  }
  for (int l = tid; l < 4096; l += 256) {
    int c = l >> 6, kq = l & 63;
    float4 v = *(const float4*)(W + (size_t)c*256 + kq*4);
    uint2 p; p.x = packbf(v.x, v.y); p.y = packbf(v.z, v.w);
    *(uint2*)&Ws[c*130 + kq*2] = p;
  }
  __syncthreads();

  float acc[4][4];
#pragma unroll
  for (int rj = 0; rj < 4; rj++)
#pragma unroll
    for (int cj = 0; cj < 4; cj++)
      acc[rj][cj] = bias[tx + 16*cj];

#pragma unroll 2
  for (int kq = 0; kq < 64; kq++) {
    float4 av[4];
#pragma unroll
    for (int rj = 0; rj < 4; rj++)
      av[rj] = *(const float4*)&As[(ty*4+rj)*260 + 4*kq];
#pragma unroll
    for (int cj = 0; cj < 4; cj++) {
      uint2 w2 = *(const uint2*)&Ws[(tx + 16*cj)*130 + 2*kq];
      float w0 = bflo(w2.x), w1 = bfhi(w2.x);
      float w2f = bflo(w2.y), w3 = bfhi(w2.y);
#pragma unroll
      for (int rj = 0; rj < 4; rj++)
        acc[rj][cj] += av[rj].x*w0 + av[rj].y*w1 + av[rj].z*w2f + av[rj].w*w3;
    }
  }

#pragma unroll
  for (int rj = 0; rj < 4; rj++) {
    int r = r0 + ty*4 + rj;
    int t = r >> 5, b = r & 31;
    size_t base = ((size_t)b * TT + t) * DD;
#pragma unroll
    for (int cj = 0; cj < 4; cj++) {
      int c = tx + 16*cj;
      float imp = acc[rj][cj];
      float xv = x[base + c], mv = mask[base + c];
      out[base + c] = xv*mv + imp*(1.0f - mv);
      out[(size_t)1048576 + base + c] = imp;
    }
  }
}

// ---------- launcher ----------
extern "C" void kernel_launch(void* const* d_in, const int* in_sizes, int n_in,
                              void* d_out, int out_size, void* d_ws, size_t ws_size,
                              hipStream_t stream) {
  const float* x     = (const float*)d_in[0];
  const float* mask  = (const float*)d_in[1];
  const float* fWi   = (const float*)d_in[2];
  const float* fbi   = (const float*)d_in[3];
  const float* fWh   = (const float*)d_in[4];
  const float* fbh   = (const float*)d_in[5];
  const float* bWi   = (const float*)d_in[6];
  const float* bbi   = (const float*)d_in[7];
  const float* bWh   = (const float*)d_in[8];
  const float* bbh   = (const float*)d_in[9];
  const float* aWin  = (const float*)d_in[10];
  const float* abin  = (const float*)d_in[11];
  const float* aWout = (const float*)d_in[12];
  const float* about = (const float*)d_in[13];
  const float* oW    = (const float*)d_in[14];
  const float* ob    = (const float*)d_in[15];
  float* out = (float*)d_out;
  float* ws  = (float*)d_ws;

  // workspace layout (f32 elems), aliased across phases:
  // [0, 12582912)        gi [16384][768] -> qkv [16384][768] -> hc2 [16384][256]
  // [12582912, 16777216) hc [16384][256] -> obuf [16384][256]
  float* gi   = ws;
  float* hc   = ws + 12582912;
  float* qkv  = ws;
  float* obuf = ws + 12582912;
  float* hc2  = ws;

  gi_kernel<<<dim3(64, 2), 256, 0, stream>>>(x, mask, fWi, fbi, bWi, bbi, gi);
  scan_kernel<<<64, 256, 0, stream>>>(gi, fWh, fbh, bWh, bbh, hc);
  mfma_gemm_kernel<<<256, 256, 0, stream>>>(hc, aWin, abin, qkv, 768);
  attn_mfma_kernel<<<256, 256, 0, stream>>>(qkv, obuf);
  mfma_gemm_kernel<<<256, 256, 0, stream>>>(obuf, aWout, about, hc2, 256);
  final_kernel<<<256, 256, 0, stream>>>(hc2, oW, ob, x, mask, out);
}